// Round 2
// baseline (309.481 us; speedup 1.0000x reference)
//
#include <hip/hip_runtime.h>
#include <stdint.h>
#include <stddef.h>

#define B_N    16384
#define NCLS_N 1000
#define C_N    1280

// workspace layout (bytes). Required ws_size >= ~52.8 MB.
#define ACC_OFF    0ULL
#define TICKET_OFF 64ULL
#define COLSUM_OFF 128ULL
#define FBT_OFF    8192ULL                         // bf16 panel [512kc][4kj][1280][8]
#define WB_OFF     41951232ULL                     // bf16 panel [40kc][4kj][1024][8] (rows >=1000 zero)
#define G_OFF      44572672ULL                     // fp32 [1280][1280]
#define H_OFF      51126272ULL                     // fp32 [1024][1024]

enum { A_NLL = 0, A_KL = 1, A_L1 = 2, A_L2SQ = 3, A_SUMSQF = 4, A_FMU2 = 5, A_GFRO = 6, A_HFRO = 7 };

typedef short s16x8 __attribute__((ext_vector_type(8)));
typedef float f32x4 __attribute__((ext_vector_type(4)));

__device__ __forceinline__ unsigned short f2bf(float f) {
    union { float f; unsigned int u; } v; v.f = f;
    unsigned int u = v.u;
    u += 0x7fffu + ((u >> 16) & 1u);   // RNE
    return (unsigned short)(u >> 16);
}

__device__ __forceinline__ float wave_red(float v) {
#pragma unroll
    for (int o = 32; o; o >>= 1) v += __shfl_down(v, o, 64);
    return v;
}

// ================= role bodies =================

// ---------------- NLL gather ----------------
__device__ __forceinline__ void nll_body(const float* __restrict__ lp,
                                         const int* __restrict__ tgt,
                                         float* __restrict__ acc, int bidx) {
    int b = bidx * 256 + threadIdx.x;
    int t = tgt[b];
    float v = lp[(size_t)b * NCLS_N + t];
    v = wave_red(v);
    __shared__ float sm_nll[4];
    int wid = threadIdx.x >> 6, lane = threadIdx.x & 63;
    if (lane == 0) sm_nll[wid] = v;
    __syncthreads();
    if (threadIdx.x == 0) atomicAdd(&acc[A_NLL], sm_nll[0] + sm_nll[1] + sm_nll[2] + sm_nll[3]);
}

// ---------------- weights: bf16 panel cast (padded to 1024 rows) + L1 + L2sq ----------------
__device__ __forceinline__ void wpass_body(const float* __restrict__ W,
                                           short* __restrict__ Wb,
                                           float* __restrict__ acc, int idx) {
    int bx = idx & 3;                           // 0..3 row-group
    int kc = idx >> 2;                          // 0..39
    int m = bx * 256 + threadIdx.x;             // 0..1023
    bool live = (m < NCLS_N);
    const float4* Wr = (const float4*)(W + (size_t)m * C_N);
    float l1 = 0.f, l2 = 0.f;
#pragma unroll
    for (int kj = 0; kj < 4; kj++) {
        s16x8 pk = { 0, 0, 0, 0, 0, 0, 0, 0 };
        if (live) {
            float4 a = Wr[kc * 8 + kj * 2];
            float4 b = Wr[kc * 8 + kj * 2 + 1];
            l1 += fabsf(a.x) + fabsf(a.y) + fabsf(a.z) + fabsf(a.w)
                + fabsf(b.x) + fabsf(b.y) + fabsf(b.z) + fabsf(b.w);
            l2 += a.x * a.x + a.y * a.y + a.z * a.z + a.w * a.w
                + b.x * b.x + b.y * b.y + b.z * b.z + b.w * b.w;
            pk[0] = (short)f2bf(a.x); pk[1] = (short)f2bf(a.y);
            pk[2] = (short)f2bf(a.z); pk[3] = (short)f2bf(a.w);
            pk[4] = (short)f2bf(b.x); pk[5] = (short)f2bf(b.y);
            pk[6] = (short)f2bf(b.z); pk[7] = (short)f2bf(b.w);
        }
        *(s16x8*)(Wb + ((size_t)(kc * 4 + kj) * 1024 + m) * 8) = pk;
    }
    l1 = wave_red(l1);
    l2 = wave_red(l2);
    __shared__ float sm_w[4][2];
    int wid = threadIdx.x >> 6, lane = threadIdx.x & 63;
    if (lane == 0) { sm_w[wid][0] = l1; sm_w[wid][1] = l2; }
    __syncthreads();
    if (threadIdx.x == 0) {
        atomicAdd(&acc[A_L1],   sm_w[0][0] + sm_w[1][0] + sm_w[2][0] + sm_w[3][0]);
        atomicAdd(&acc[A_L2SQ], sm_w[0][1] + sm_w[1][1] + sm_w[2][1] + sm_w[3][1]);
    }
}

// ---------------- features: bf16 panel transpose + column sums + sum of squares ----------------
// one 32-k chunk per block (2560 blocks): 4x the wave count of round-1 for latency hiding.
__device__ __forceinline__ void fpass_body(const float* __restrict__ F,
                                           short* __restrict__ Fbt,
                                           float* __restrict__ colsum,
                                           float* __restrict__ acc, int idx) {
    int bx = idx % 5;                           // 0..4 column group
    int kc = idx / 5;                           // 0..511
    int c = bx * 256 + threadIdx.x;             // 0..1279
    int kbase = kc * 32;
    float cs = 0.f, sq = 0.f;
#pragma unroll
    for (int kj = 0; kj < 4; kj++) {
        float v[8];
#pragma unroll
        for (int e = 0; e < 8; e++) v[e] = F[(size_t)(kbase + kj * 8 + e) * C_N + c];
        s16x8 pk;
#pragma unroll
        for (int e = 0; e < 8; e++) {
            cs += v[e];
            sq += v[e] * v[e];
            pk[e] = (short)f2bf(v[e]);
        }
        *(s16x8*)(Fbt + ((size_t)(kc * 4 + kj) * C_N + c) * 8) = pk;
    }
    atomicAdd(&colsum[c], cs);
    sq = wave_red(sq);
    __shared__ float sm_f[4];
    int wid = threadIdx.x >> 6, lane = threadIdx.x & 63;
    if (lane == 0) sm_f[wid] = sq;
    __syncthreads();
    if (threadIdx.x == 0) atomicAdd(&acc[A_SUMSQF], sm_f[0] + sm_f[1] + sm_f[2] + sm_f[3]);
}

// ---------------- per-row: KL term + ||F mu||^2 term ----------------
__device__ __forceinline__ void klpass_body(const float* __restrict__ F,
                                            const float* __restrict__ colsum,
                                            float* __restrict__ acc, int idx) {
    int wid = threadIdx.x >> 6, lane = threadIdx.x & 63;
    int gwave = idx * 4 + wid;                   // 0..4095
    const float4* M = (const float4*)colsum;

    float kl_acc = 0.f, fmu_acc = 0.f;
    for (int b = gwave; b < B_N; b += 4096) {
        const float4* Fr = (const float4*)(F + (size_t)b * C_N);
        float s = 0.f, tt = 0.f, sf = 0.f, dp = 0.f;
#pragma unroll
        for (int i = 0; i < 5; i++) {
            float4 f = Fr[lane + 64 * i];
            float4 m = M[lane + 64 * i];
            float e0 = __expf(f.x), e1 = __expf(f.y), e2 = __expf(f.z), e3 = __expf(f.w);
            s  += e0 + e1 + e2 + e3;
            tt += e0 * f.x + e1 * f.y + e2 * f.z + e3 * f.w;
            sf += f.x + f.y + f.z + f.w;
            dp += f.x * m.x + f.y * m.y + f.z * m.z + f.w * m.w;
        }
        s = wave_red(s); tt = wave_red(tt); sf = wave_red(sf); dp = wave_red(dp);
        if (lane == 0) {
            kl_acc += (float)C_N * (tt / s) - sf;
            float dot = dp * (1.f / (float)B_N);  // (F mu)_b, mu = colsum/B
            fmu_acc += dot * dot;
        }
    }
    __shared__ float sm_kl[4][2];
    if (lane == 0) { sm_kl[wid][0] = kl_acc; sm_kl[wid][1] = fmu_acc; }
    __syncthreads();
    if (threadIdx.x == 0) {
        atomicAdd(&acc[A_KL],   sm_kl[0][0] + sm_kl[1][0] + sm_kl[2][0] + sm_kl[3][0]);
        atomicAdd(&acc[A_FMU2], sm_kl[0][1] + sm_kl[1][1] + sm_kl[2][1] + sm_kl[3][1]);
    }
}

// ---------------- bf16 Gram: S += X X^T, 2-phase pipelined (T3 minimum recipe) ----------------
// X: panel layout [kc][kj][Mp][8] bf16 (k = kc*32 + kj*8 + e).
// 128x128 tile, 4 waves (2x2 of 64x64), BK=32, 16x16x32 MFMA.
// LDS [128 rows][4 slots][8] with XOR swizzle: slot s at row r holds kj = s ^ (r&3).
// Double-buffered as FOUR distinct static arrays + 2x-unrolled body so every LDS access
// has compile-time buffer identity (NoAlias => legalizer can't insert vmcnt(0) before
// the ds_reads of the live buffer while next-step global_load_lds is in flight).
// ONE barrier per K-step: stage(next) -> ds_read+MFMA(cur) -> __syncthreads (drains vmcnt).
// Requires nt = chunkK/32 EVEN (G: 32, H: 10).
__device__ __forceinline__ void gram_body(const short* __restrict__ X,
                                          float* __restrict__ S,
                                          int Mp, int T, int ntri, int chunkK, int bidx) {
    __shared__ __align__(16) short A0[128 * 32];
    __shared__ __align__(16) short A1[128 * 32];
    __shared__ __align__(16) short B0[128 * 32];
    __shared__ __align__(16) short B1[128 * 32];
    int tid = threadIdx.x;
    int tile = bidx % ntri;
    int kc_blk = bidx / ntri;
    int bi = 0, rem = tile;
    while (rem >= T - bi) { rem -= T - bi; bi++; }
    int bj = bi + rem;
    int i0 = bi * 128, j0 = bj * 128;
    bool same = (bi == bj);

    int wave = tid >> 6, lane = tid & 63;
    int wm = wave >> 1, wn = wave & 1;
    int quad = lane >> 4, l16 = lane & 15;

    // per-thread staging constants: thread covers g0 = tid, g1 = 256+tid
    const size_t kstep = (size_t)Mp * 32;       // shorts per kc step (4*Mp*8)
    const short *pa0, *pa1, *pb0, *pb1;
    int lo0 = tid * 8, lo1 = (256 + tid) * 8;
    {
        int g0 = tid, g1 = 256 + tid;
        int r0 = g0 >> 2, r1 = g1 >> 2;
        int kj0 = (g0 & 3) ^ (r0 & 3), kj1 = (g1 & 3) ^ (r1 & 3);
        size_t base = (size_t)(kc_blk * chunkK >> 5) * kstep;
        pa0 = X + base + ((size_t)kj0 * Mp + i0 + r0) * 8;
        pa1 = X + base + ((size_t)kj1 * Mp + i0 + r1) * 8;
        pb0 = X + base + ((size_t)kj0 * Mp + j0 + r0) * 8;
        pb1 = X + base + ((size_t)kj1 * Mp + j0 + r1) * 8;
    }

    f32x4 acc[4][4];
#pragma unroll
    for (int i = 0; i < 4; i++)
#pragma unroll
        for (int j = 0; j < 4; j++) acc[i][j] = { 0.f, 0.f, 0.f, 0.f };

    auto stage = [&](short* Ad, short* Bd) {
        __builtin_amdgcn_global_load_lds((const __attribute__((address_space(1))) unsigned int*)pa0,
                                         (__attribute__((address_space(3))) unsigned int*)(Ad + lo0), 16, 0, 0);
        __builtin_amdgcn_global_load_lds((const __attribute__((address_space(1))) unsigned int*)pa1,
                                         (__attribute__((address_space(3))) unsigned int*)(Ad + lo1), 16, 0, 0);
        if (!same) {
            __builtin_amdgcn_global_load_lds((const __attribute__((address_space(1))) unsigned int*)pb0,
                                             (__attribute__((address_space(3))) unsigned int*)(Bd + lo0), 16, 0, 0);
            __builtin_amdgcn_global_load_lds((const __attribute__((address_space(1))) unsigned int*)pb1,
                                             (__attribute__((address_space(3))) unsigned int*)(Bd + lo1), 16, 0, 0);
        }
        pa0 += kstep; pa1 += kstep; pb0 += kstep; pb1 += kstep;
    };

    auto compute = [&](const short* Ab, const short* Bb) {
        s16x8 af[4], bfr[4];
#pragma unroll
        for (int f = 0; f < 4; f++) {
            int mrow = wm * 64 + f * 16 + l16;
            af[f] = *(const s16x8*)(Ab + mrow * 32 + (quad ^ (mrow & 3)) * 8);
            int nrow = wn * 64 + f * 16 + l16;
            bfr[f] = *(const s16x8*)(Bb + nrow * 32 + (quad ^ (nrow & 3)) * 8);
        }
#pragma unroll
        for (int i = 0; i < 4; i++)
#pragma unroll
            for (int j = 0; j < 4; j++)
                acc[i][j] = __builtin_amdgcn_mfma_f32_16x16x32_bf16(af[i], bfr[j], acc[i][j], 0, 0, 0);
    };

    int nt = chunkK >> 5;                        // even by construction
    stage(A0, B0);                               // prologue: k-step 0
    __syncthreads();                             // vmcnt(0) drain + barrier
    for (int t = 0; t < nt; t += 2) {
        stage(A1, B1);                           // k-step t+1 in flight under compute
        compute(A0, same ? A0 : B0);
        __syncthreads();                         // drains vmcnt -> A1/B1 ready; A0/B0 reads done
        if (t + 2 < nt) stage(A0, B0);           // k-step t+2
        compute(A1, same ? A1 : B1);
        __syncthreads();
    }

#pragma unroll
    for (int i = 0; i < 4; i++)
#pragma unroll
        for (int j = 0; j < 4; j++)
#pragma unroll
            for (int r = 0; r < 4; r++) {
                int grow = i0 + wm * 64 + i * 16 + quad * 4 + r;
                int gcol = j0 + wn * 64 + j * 16 + l16;
                atomicAdd(&S[(size_t)grow * Mp + gcol], acc[i][j][r]);
            }
}

// ---------------- Frobenius^2 over computed triangular tiles (off-diag weighted 2x) ----------------
__device__ __forceinline__ void fro_tile(const float* __restrict__ S,
                                         int Mp, int T, int tile, float* __restrict__ slot) {
    int bi = 0, rem = tile;
    while (rem >= T - bi) { rem -= T - bi; bi++; }
    int bj = bi + rem;
    size_t base = (size_t)bi * 128 * Mp + (size_t)bj * 128;
    float sum = 0.f;
    for (int l = threadIdx.x * 4; l < 128 * 128; l += 1024) {
        int row = l >> 7, col = l & 127;
        float4 v = *(const float4*)(S + base + (size_t)row * Mp + col);
        sum += v.x * v.x + v.y * v.y + v.z * v.z + v.w * v.w;
    }
    sum = wave_red(sum);
    __shared__ float sm_fro[4];
    int wid = threadIdx.x >> 6, lane = threadIdx.x & 63;
    if (lane == 0) sm_fro[wid] = sum;
    __syncthreads();
    if (threadIdx.x == 0) {
        float w = (bi == bj) ? 1.f : 2.f;
        atomicAdd(slot, w * (sm_fro[0] + sm_fro[1] + sm_fro[2] + sm_fro[3]));
    }
}

// ================= fused kernels =================

// K1: all input-independent work. blocks: [0,2560) fpass | [2560,2720) wpass
//     | [2720,2784) nll | [2784,2884) zero G | [2884,2948) zero H.
__global__ __launch_bounds__(256) void prep_kernel(const float* __restrict__ lp,
                                                   const int* __restrict__ tgt,
                                                   const float* __restrict__ W,
                                                   const float* __restrict__ F,
                                                   short* __restrict__ Wb,
                                                   short* __restrict__ Fbt,
                                                   float* __restrict__ colsum,
                                                   float* __restrict__ acc,
                                                   float* __restrict__ G,
                                                   float* __restrict__ H) {
    int b = blockIdx.x;
    if (b < 2560) {
        fpass_body(F, Fbt, colsum, acc, b);
    } else if (b < 2720) {
        wpass_body(W, Wb, acc, b - 2560);
    } else if (b < 2784) {
        nll_body(lp, tgt, acc, b - 2720);
    } else if (b < 2884) {
        float4* p = (float4*)G + (size_t)(b - 2784) * 4096;   // 100 * 64KB = 6.5536 MB exact
        float4 z = { 0.f, 0.f, 0.f, 0.f };
        for (int i = threadIdx.x; i < 4096; i += 256) p[i] = z;
    } else {
        float4* p = (float4*)H + (size_t)(b - 2884) * 4096;   // 64 * 64KB = 4.1943 MB exact
        float4 z = { 0.f, 0.f, 0.f, 0.f };
        for (int i = threadIdx.x; i < 4096; i += 256) p[i] = z;
    }
}

// K2: blocks: [0,880) gram G | [880,1904) klpass | [1904,2048) gram H.
__global__ __launch_bounds__(256) void main_kernel(const short* __restrict__ Fbt,
                                                   float* __restrict__ G,
                                                   const short* __restrict__ Wb,
                                                   float* __restrict__ H,
                                                   const float* __restrict__ F,
                                                   const float* __restrict__ colsum,
                                                   float* __restrict__ acc) {
    int b = blockIdx.x;
    if (b < 880) {
        gram_body(Fbt, G, C_N, 10, 55, 1024, b);        // Mp=1280, T=10, ntri=55, ksplit=16 (nt=32)
    } else if (b < 1904) {
        klpass_body(F, colsum, acc, b - 880);
    } else {
        gram_body(Wb, H, 1024, 8, 36, 320, b - 1904);   // Mp=1024, T=8, ntri=36, ksplit=4 (nt=10)
    }
}

// K3: both Frobenius reductions + last-block final combine (ticket pattern).
// blocks: [0,55) G | [55,91) H.
__global__ __launch_bounds__(256) void fro_final_kernel(const float* __restrict__ G,
                                                        const float* __restrict__ H,
                                                        float* __restrict__ acc,
                                                        const float* __restrict__ colsum,
                                                        unsigned* __restrict__ ticket,
                                                        float* __restrict__ out) {
    int b = blockIdx.x;
    if (b < 55) fro_tile(G, C_N, 10, b, acc + A_GFRO);
    else        fro_tile(H, 1024, 8, b - 55, acc + A_HFRO);

    __shared__ int amlast;
    if (threadIdx.x == 0) {
        __threadfence();                               // order my fro atomicAdd before ticket
        unsigned prev = atomicAdd(ticket, 1u);
        amlast = (prev == 90u);
    }
    __syncthreads();
    if (!amlast) return;
    __threadfence();                                   // acquire side

    // final combine (winner block only). colsum & most acc slots are prior-dispatch
    // (kernel-boundary coherent); A_GFRO/A_HFRO are same-dispatch -> atomic read.
    float s = 0.f;
    for (int c = threadIdx.x; c < C_N; c += 256) { float v = colsum[c]; s += v * v; }
    s = wave_red(s);
    __shared__ float sm[4];
    int wid = threadIdx.x >> 6, lane = threadIdx.x & 63;
    if (lane == 0) sm[wid] = s;
    __syncthreads();
    if (threadIdx.x == 0) {
        double musq_raw = (double)(sm[0] + sm[1] + sm[2] + sm[3]);   // sum colsum^2 = B^2 * ||mu||^2
        double Bd = (double)B_N;
        double gfro = (double)atomicAdd(&acc[A_GFRO], 0.0f);
        double hfro = (double)atomicAdd(&acc[A_HFRO], 0.0f);
        double nll = -((double)acc[A_NLL] / Bd);
        double kl  = (double)acc[A_KL] / Bd;
        double trG = (double)acc[A_SUMSQF];
        double musq = musq_raw / (Bd * Bd);
        double cov = gfro / (Bd * Bd)
                   - (2.0 / Bd) * (double)acc[A_FMU2]
                   + musq * musq
                   - 2.0 * (trG / Bd - musq)
                   + (double)C_N;
        double ortho = hfro - 2.0 * (double)acc[A_L2SQ] + (double)NCLS_N;
        double loss = 1.0 * nll + 0.2 * kl + 0.2 * cov + 0.1 * ortho
                    + 0.1 * (double)acc[A_L1] + 0.1 * sqrt((double)acc[A_L2SQ]);
        out[0] = (float)loss;
    }
}

extern "C" void kernel_launch(void* const* d_in, const int* in_sizes, int n_in,
                              void* d_out, int out_size, void* d_ws, size_t ws_size,
                              hipStream_t stream) {
    (void)in_sizes; (void)n_in; (void)out_size; (void)ws_size;
    const float* output_lp = (const float*)d_in[0];
    const int*   target    = (const int*)d_in[1];
    const float* W         = (const float*)d_in[2];
    const float* F         = (const float*)d_in[3];

    char*     ws     = (char*)d_ws;
    float*    acc    = (float*)(ws + ACC_OFF);
    unsigned* ticket = (unsigned*)(ws + TICKET_OFF);
    float*    colsum = (float*)(ws + COLSUM_OFF);
    short*    Fbt    = (short*)(ws + FBT_OFF);
    short*    Wb     = (short*)(ws + WB_OFF);
    float*    G      = (float*)(ws + G_OFF);
    float*    H      = (float*)(ws + H_OFF);

    // acc + ticket + colsum must be zero BEFORE K1's atomics (ws poisoned before launch).
    // G/H are zeroed by K1 roles (only touched by K2 atomics — cross-launch ordering).
    hipMemsetAsync(ws, 0, 8192, stream);

    prep_kernel<<<2948, 256, 0, stream>>>(output_lp, target, W, F, Wb, Fbt, colsum, acc, G, H);
    main_kernel<<<2048, 256, 0, stream>>>(Fbt, G, Wb, H, F, colsum, acc);
    fro_final_kernel<<<91, 256, 0, stream>>>(G, H, acc, colsum, ticket, (float*)d_out);
}

// Round 3
// 297.186 us; speedup vs baseline: 1.0414x; 1.0414x over previous
//
#include <hip/hip_runtime.h>
#include <stdint.h>
#include <stddef.h>

#define B_N    16384
#define NCLS_N 1000
#define C_N    1280

// workspace layout (bytes). Required ws_size >= ~52.8 MB.
#define ACC_OFF    0ULL
#define TICKET_OFF 64ULL
#define COLSUM_OFF 128ULL
#define FBT_OFF    8192ULL                         // bf16 panel [512kc][4kj][1280][8]
#define WB_OFF     41951232ULL                     // bf16 panel [40kc][4kj][1024][8] (rows >=1000 zero)
#define G_OFF      44572672ULL                     // fp32 [1280][1280]
#define H_OFF      51126272ULL                     // fp32 [1024][1024]

enum { A_NLL = 0, A_KL = 1, A_L1 = 2, A_L2SQ = 3, A_SUMSQF = 4, A_FMU2 = 5, A_GFRO = 6, A_HFRO = 7 };

typedef short s16x8 __attribute__((ext_vector_type(8)));
typedef float f32x4 __attribute__((ext_vector_type(4)));

__device__ __forceinline__ unsigned short f2bf(float f) {
    union { float f; unsigned int u; } v; v.f = f;
    unsigned int u = v.u;
    u += 0x7fffu + ((u >> 16) & 1u);   // RNE
    return (unsigned short)(u >> 16);
}

__device__ __forceinline__ float wave_red(float v) {
#pragma unroll
    for (int o = 32; o; o >>= 1) v += __shfl_down(v, o, 64);
    return v;
}

// ================= role bodies =================

// ---------------- NLL gather ----------------
__device__ __forceinline__ void nll_body(const float* __restrict__ lp,
                                         const int* __restrict__ tgt,
                                         float* __restrict__ acc, int bidx) {
    int b = bidx * 256 + threadIdx.x;
    int t = tgt[b];
    float v = lp[(size_t)b * NCLS_N + t];
    v = wave_red(v);
    __shared__ float sm_nll[4];
    int wid = threadIdx.x >> 6, lane = threadIdx.x & 63;
    if (lane == 0) sm_nll[wid] = v;
    __syncthreads();
    if (threadIdx.x == 0) atomicAdd(&acc[A_NLL], sm_nll[0] + sm_nll[1] + sm_nll[2] + sm_nll[3]);
}

// ---------------- weights: bf16 panel cast (padded to 1024 rows) + L1 + L2sq ----------------
__device__ __forceinline__ void wpass_body(const float* __restrict__ W,
                                           short* __restrict__ Wb,
                                           float* __restrict__ acc, int idx) {
    int bx = idx & 3;                           // 0..3 row-group
    int kc = idx >> 2;                          // 0..39
    int m = bx * 256 + threadIdx.x;             // 0..1023
    bool live = (m < NCLS_N);
    const float4* Wr = (const float4*)(W + (size_t)m * C_N);
    float l1 = 0.f, l2 = 0.f;
#pragma unroll
    for (int kj = 0; kj < 4; kj++) {
        s16x8 pk = { 0, 0, 0, 0, 0, 0, 0, 0 };
        if (live) {
            float4 a = Wr[kc * 8 + kj * 2];
            float4 b = Wr[kc * 8 + kj * 2 + 1];
            l1 += fabsf(a.x) + fabsf(a.y) + fabsf(a.z) + fabsf(a.w)
                + fabsf(b.x) + fabsf(b.y) + fabsf(b.z) + fabsf(b.w);
            l2 += a.x * a.x + a.y * a.y + a.z * a.z + a.w * a.w
                + b.x * b.x + b.y * b.y + b.z * b.z + b.w * b.w;
            pk[0] = (short)f2bf(a.x); pk[1] = (short)f2bf(a.y);
            pk[2] = (short)f2bf(a.z); pk[3] = (short)f2bf(a.w);
            pk[4] = (short)f2bf(b.x); pk[5] = (short)f2bf(b.y);
            pk[6] = (short)f2bf(b.z); pk[7] = (short)f2bf(b.w);
        }
        *(s16x8*)(Wb + ((size_t)(kc * 4 + kj) * 1024 + m) * 8) = pk;
    }
    l1 = wave_red(l1);
    l2 = wave_red(l2);
    __shared__ float sm_w[4][2];
    int wid = threadIdx.x >> 6, lane = threadIdx.x & 63;
    if (lane == 0) { sm_w[wid][0] = l1; sm_w[wid][1] = l2; }
    __syncthreads();
    if (threadIdx.x == 0) {
        atomicAdd(&acc[A_L1],   sm_w[0][0] + sm_w[1][0] + sm_w[2][0] + sm_w[3][0]);
        atomicAdd(&acc[A_L2SQ], sm_w[0][1] + sm_w[1][1] + sm_w[2][1] + sm_w[3][1]);
    }
}

// ---------------- features: bf16 panel transpose + column sums + sum of squares ----------------
// round-1 shape (4 chunks of 32 k per block, 640 blocks): round-2's 4x split regressed ~12us.
__device__ __forceinline__ void fpass_body(const float* __restrict__ F,
                                           short* __restrict__ Fbt,
                                           float* __restrict__ colsum,
                                           float* __restrict__ acc, int idx) {
    int bx = idx % 5;                           // 0..4 column group
    int by = idx / 5;                           // 0..127
    int c = bx * 256 + threadIdx.x;             // 0..1279
    int kc0 = by * 4;                           // 4 chunks of 32 k per block
    float cs = 0.f, sq = 0.f;
    for (int ch = 0; ch < 4; ch++) {
        int kc = kc0 + ch;
        int kbase = kc * 32;
#pragma unroll
        for (int kj = 0; kj < 4; kj++) {
            float v[8];
#pragma unroll
            for (int e = 0; e < 8; e++) v[e] = F[(size_t)(kbase + kj * 8 + e) * C_N + c];
            s16x8 pk;
#pragma unroll
            for (int e = 0; e < 8; e++) {
                cs += v[e];
                sq += v[e] * v[e];
                pk[e] = (short)f2bf(v[e]);
            }
            *(s16x8*)(Fbt + ((size_t)(kc * 4 + kj) * C_N + c) * 8) = pk;
        }
    }
    atomicAdd(&colsum[c], cs);
    sq = wave_red(sq);
    __shared__ float sm_f[4];
    int wid = threadIdx.x >> 6, lane = threadIdx.x & 63;
    if (lane == 0) sm_f[wid] = sq;
    __syncthreads();
    if (threadIdx.x == 0) atomicAdd(&acc[A_SUMSQF], sm_f[0] + sm_f[1] + sm_f[2] + sm_f[3]);
}

// ---------------- per-row: KL term + ||F mu||^2 term ----------------
__device__ __forceinline__ void klpass_body(const float* __restrict__ F,
                                            const float* __restrict__ colsum,
                                            float* __restrict__ acc, int idx) {
    int wid = threadIdx.x >> 6, lane = threadIdx.x & 63;
    int gwave = idx * 4 + wid;                   // 0..4095
    const float4* M = (const float4*)colsum;

    float kl_acc = 0.f, fmu_acc = 0.f;
    for (int b = gwave; b < B_N; b += 4096) {
        const float4* Fr = (const float4*)(F + (size_t)b * C_N);
        float s = 0.f, tt = 0.f, sf = 0.f, dp = 0.f;
#pragma unroll
        for (int i = 0; i < 5; i++) {
            float4 f = Fr[lane + 64 * i];
            float4 m = M[lane + 64 * i];
            float e0 = __expf(f.x), e1 = __expf(f.y), e2 = __expf(f.z), e3 = __expf(f.w);
            s  += e0 + e1 + e2 + e3;
            tt += e0 * f.x + e1 * f.y + e2 * f.z + e3 * f.w;
            sf += f.x + f.y + f.z + f.w;
            dp += f.x * m.x + f.y * m.y + f.z * m.z + f.w * m.w;
        }
        s = wave_red(s); tt = wave_red(tt); sf = wave_red(sf); dp = wave_red(dp);
        if (lane == 0) {
            kl_acc += (float)C_N * (tt / s) - sf;
            float dot = dp * (1.f / (float)B_N);  // (F mu)_b, mu = colsum/B
            fmu_acc += dot * dot;
        }
    }
    __shared__ float sm_kl[4][2];
    if (lane == 0) { sm_kl[wid][0] = kl_acc; sm_kl[wid][1] = fmu_acc; }
    __syncthreads();
    if (threadIdx.x == 0) {
        atomicAdd(&acc[A_KL],   sm_kl[0][0] + sm_kl[1][0] + sm_kl[2][0] + sm_kl[3][0]);
        atomicAdd(&acc[A_FMU2], sm_kl[0][1] + sm_kl[1][1] + sm_kl[2][1] + sm_kl[3][1]);
    }
}

// ---------------- bf16 Gram: S += X X^T, 2-phase pipelined, XCD-local K-chunks ----------------
// X: panel layout [kc][kj][Mp][8] bf16 (k = kc*32 + kj*8 + e).
// 128x128 tile, 4 waves (2x2 of 64x64), BK=32, 16x16x32 MFMA.
// LDS [128 rows][4 slots][8] with XOR swizzle: slot s at row r holds kj = s ^ (r&3).
// Double-buffered as FOUR distinct static arrays (compile-time buffer identity => NoAlias).
// Caller passes (tile, kc_blk) decoded so that kc_blk == blockIdx%ksplit: XCD = blockIdx%8
// == kc_blk%8 -> each XCD's L2 only serves its own K-regions of the panel (T1 mechanism:
// panel 41.9MB streams through every 4MB XCD-L2 with the old tile-minor decode; now each
// XCD re-reads ~5.2MB -> stage loads mostly L2-hit, latency ~250cyc hidden by 2-phase).
__device__ __forceinline__ void gram_body(const short* __restrict__ X,
                                          float* __restrict__ S,
                                          int Mp, int T, int tile, int kc_blk, int chunkK) {
    __shared__ __align__(16) short A0[128 * 32];
    __shared__ __align__(16) short A1[128 * 32];
    __shared__ __align__(16) short B0[128 * 32];
    __shared__ __align__(16) short B1[128 * 32];
    int tid = threadIdx.x;
    int bi = 0, rem = tile;
    while (rem >= T - bi) { rem -= T - bi; bi++; }
    int bj = bi + rem;
    int i0 = bi * 128, j0 = bj * 128;
    bool same = (bi == bj);

    int wave = tid >> 6, lane = tid & 63;
    int wm = wave >> 1, wn = wave & 1;
    int quad = lane >> 4, l16 = lane & 15;

    // per-thread staging constants: thread covers g0 = tid, g1 = 256+tid
    const size_t kstep = (size_t)Mp * 32;       // shorts per kc step (4*Mp*8)
    const short *pa0, *pa1, *pb0, *pb1;
    int lo0 = tid * 8, lo1 = (256 + tid) * 8;
    {
        int g0 = tid, g1 = 256 + tid;
        int r0 = g0 >> 2, r1 = g1 >> 2;
        int kj0 = (g0 & 3) ^ (r0 & 3), kj1 = (g1 & 3) ^ (r1 & 3);
        size_t base = (size_t)(kc_blk * chunkK >> 5) * kstep;
        pa0 = X + base + ((size_t)kj0 * Mp + i0 + r0) * 8;
        pa1 = X + base + ((size_t)kj1 * Mp + i0 + r1) * 8;
        pb0 = X + base + ((size_t)kj0 * Mp + j0 + r0) * 8;
        pb1 = X + base + ((size_t)kj1 * Mp + j0 + r1) * 8;
    }

    f32x4 acc[4][4];
#pragma unroll
    for (int i = 0; i < 4; i++)
#pragma unroll
        for (int j = 0; j < 4; j++) acc[i][j] = { 0.f, 0.f, 0.f, 0.f };

    auto stage = [&](short* Ad, short* Bd) {
        __builtin_amdgcn_global_load_lds((const __attribute__((address_space(1))) unsigned int*)pa0,
                                         (__attribute__((address_space(3))) unsigned int*)(Ad + lo0), 16, 0, 0);
        __builtin_amdgcn_global_load_lds((const __attribute__((address_space(1))) unsigned int*)pa1,
                                         (__attribute__((address_space(3))) unsigned int*)(Ad + lo1), 16, 0, 0);
        if (!same) {
            __builtin_amdgcn_global_load_lds((const __attribute__((address_space(1))) unsigned int*)pb0,
                                             (__attribute__((address_space(3))) unsigned int*)(Bd + lo0), 16, 0, 0);
            __builtin_amdgcn_global_load_lds((const __attribute__((address_space(1))) unsigned int*)pb1,
                                             (__attribute__((address_space(3))) unsigned int*)(Bd + lo1), 16, 0, 0);
        }
        pa0 += kstep; pa1 += kstep; pb0 += kstep; pb1 += kstep;
    };

    auto compute = [&](const short* Ab, const short* Bb) {
        s16x8 af[4], bfr[4];
#pragma unroll
        for (int f = 0; f < 4; f++) {
            int mrow = wm * 64 + f * 16 + l16;
            af[f] = *(const s16x8*)(Ab + mrow * 32 + (quad ^ (mrow & 3)) * 8);
            int nrow = wn * 64 + f * 16 + l16;
            bfr[f] = *(const s16x8*)(Bb + nrow * 32 + (quad ^ (nrow & 3)) * 8);
        }
        // T5: gram waves co-reside with klpass VALU waves -> prefer the MFMA wave
        __builtin_amdgcn_s_setprio(1);
#pragma unroll
        for (int i = 0; i < 4; i++)
#pragma unroll
            for (int j = 0; j < 4; j++)
                acc[i][j] = __builtin_amdgcn_mfma_f32_16x16x32_bf16(af[i], bfr[j], acc[i][j], 0, 0, 0);
        __builtin_amdgcn_s_setprio(0);
    };

    int nt = chunkK >> 5;                        // even by construction
    stage(A0, B0);                               // prologue: k-step 0
    __syncthreads();                             // vmcnt(0) drain + barrier
    for (int t = 0; t < nt; t += 2) {
        stage(A1, B1);                           // k-step t+1 in flight under compute
        compute(A0, same ? A0 : B0);
        __syncthreads();                         // drains vmcnt -> A1/B1 ready; A0/B0 reads done
        if (t + 2 < nt) stage(A0, B0);           // k-step t+2
        compute(A1, same ? A1 : B1);
        __syncthreads();
    }

#pragma unroll
    for (int i = 0; i < 4; i++)
#pragma unroll
        for (int j = 0; j < 4; j++)
#pragma unroll
            for (int r = 0; r < 4; r++) {
                int grow = i0 + wm * 64 + i * 16 + quad * 4 + r;
                int gcol = j0 + wn * 64 + j * 16 + l16;
                atomicAdd(&S[(size_t)grow * Mp + gcol], acc[i][j][r]);
            }
}

// ---------------- Frobenius^2 over computed triangular tiles (off-diag weighted 2x) ----------------
__device__ __forceinline__ void fro_tile(const float* __restrict__ S,
                                         int Mp, int T, int tile, float* __restrict__ slot) {
    int bi = 0, rem = tile;
    while (rem >= T - bi) { rem -= T - bi; bi++; }
    int bj = bi + rem;
    size_t base = (size_t)bi * 128 * Mp + (size_t)bj * 128;
    float sum = 0.f;
    for (int l = threadIdx.x * 4; l < 128 * 128; l += 1024) {
        int row = l >> 7, col = l & 127;
        float4 v = *(const float4*)(S + base + (size_t)row * Mp + col);
        sum += v.x * v.x + v.y * v.y + v.z * v.z + v.w * v.w;
    }
    sum = wave_red(sum);
    __shared__ float sm_fro[4];
    int wid = threadIdx.x >> 6, lane = threadIdx.x & 63;
    if (lane == 0) sm_fro[wid] = sum;
    __syncthreads();
    if (threadIdx.x == 0) {
        float w = (bi == bj) ? 1.f : 2.f;
        atomicAdd(slot, w * (sm_fro[0] + sm_fro[1] + sm_fro[2] + sm_fro[3]));
    }
}

// ================= fused kernels =================

// K1: all input-independent work. blocks: [0,640) fpass | [640,800) wpass
//     | [800,864) nll | [864,964) zero G | [964,1028) zero H.
__global__ __launch_bounds__(256) void prep_kernel(const float* __restrict__ lp,
                                                   const int* __restrict__ tgt,
                                                   const float* __restrict__ W,
                                                   const float* __restrict__ F,
                                                   short* __restrict__ Wb,
                                                   short* __restrict__ Fbt,
                                                   float* __restrict__ colsum,
                                                   float* __restrict__ acc,
                                                   float* __restrict__ G,
                                                   float* __restrict__ H) {
    int b = blockIdx.x;
    if (b < 640) {
        fpass_body(F, Fbt, colsum, acc, b);
    } else if (b < 800) {
        wpass_body(W, Wb, acc, b - 640);
    } else if (b < 864) {
        nll_body(lp, tgt, acc, b - 800);
    } else if (b < 964) {
        float4* p = (float4*)G + (size_t)(b - 864) * 4096;   // 100 * 64KB = 6.5536 MB exact
        float4 z = { 0.f, 0.f, 0.f, 0.f };
        for (int i = threadIdx.x; i < 4096; i += 256) p[i] = z;
    } else {
        float4* p = (float4*)H + (size_t)(b - 964) * 4096;   // 64 * 64KB = 4.1943 MB exact
        float4 z = { 0.f, 0.f, 0.f, 0.f };
        for (int i = threadIdx.x; i < 4096; i += 256) p[i] = z;
    }
}

// K2: blocks: [0,880) gram G | [880,1904) klpass | [1904,2048) gram H.
// gram decodes are kc-minor: kc_blk = local % ksplit so XCD(=blockIdx%8) owns fixed K-regions.
__global__ __launch_bounds__(256) void main_kernel(const short* __restrict__ Fbt,
                                                   float* __restrict__ G,
                                                   const short* __restrict__ Wb,
                                                   float* __restrict__ H,
                                                   const float* __restrict__ F,
                                                   const float* __restrict__ colsum,
                                                   float* __restrict__ acc) {
    int b = blockIdx.x;
    if (b < 880) {
        gram_body(Fbt, G, C_N, 10, b >> 4, b & 15, 1024);        // Mp=1280, T=10, 55 tiles x 16 kc (nt=32)
    } else if (b < 1904) {
        klpass_body(F, colsum, acc, b - 880);
    } else {
        int l = b - 1904;                                        // 1904 % 8 == 0: local%8 == blockIdx%8
        gram_body(Wb, H, 1024, 8, l >> 2, l & 3, 320);           // Mp=1024, T=8, 36 tiles x 4 kc (nt=10)
    }
}

// K3: both Frobenius reductions + last-block final combine (ticket pattern).
// blocks: [0,55) G | [55,91) H.
__global__ __launch_bounds__(256) void fro_final_kernel(const float* __restrict__ G,
                                                        const float* __restrict__ H,
                                                        float* __restrict__ acc,
                                                        const float* __restrict__ colsum,
                                                        unsigned* __restrict__ ticket,
                                                        float* __restrict__ out) {
    int b = blockIdx.x;
    if (b < 55) fro_tile(G, C_N, 10, b, acc + A_GFRO);
    else        fro_tile(H, 1024, 8, b - 55, acc + A_HFRO);

    __shared__ int amlast;
    if (threadIdx.x == 0) {
        __threadfence();                               // order my fro atomicAdd before ticket
        unsigned prev = atomicAdd(ticket, 1u);
        amlast = (prev == 90u);
    }
    __syncthreads();
    if (!amlast) return;
    __threadfence();                                   // acquire side

    // final combine (winner block only). colsum & most acc slots are prior-dispatch
    // (kernel-boundary coherent); A_GFRO/A_HFRO are same-dispatch -> atomic read.
    float s = 0.f;
    for (int c = threadIdx.x; c < C_N; c += 256) { float v = colsum[c]; s += v * v; }
    s = wave_red(s);
    __shared__ float sm[4];
    int wid = threadIdx.x >> 6, lane = threadIdx.x & 63;
    if (lane == 0) sm[wid] = s;
    __syncthreads();
    if (threadIdx.x == 0) {
        double musq_raw = (double)(sm[0] + sm[1] + sm[2] + sm[3]);   // sum colsum^2 = B^2 * ||mu||^2
        double Bd = (double)B_N;
        double gfro = (double)atomicAdd(&acc[A_GFRO], 0.0f);
        double hfro = (double)atomicAdd(&acc[A_HFRO], 0.0f);
        double nll = -((double)acc[A_NLL] / Bd);
        double kl  = (double)acc[A_KL] / Bd;
        double trG = (double)acc[A_SUMSQF];
        double musq = musq_raw / (Bd * Bd);
        double cov = gfro / (Bd * Bd)
                   - (2.0 / Bd) * (double)acc[A_FMU2]
                   + musq * musq
                   - 2.0 * (trG / Bd - musq)
                   + (double)C_N;
        double ortho = hfro - 2.0 * (double)acc[A_L2SQ] + (double)NCLS_N;
        double loss = 1.0 * nll + 0.2 * kl + 0.2 * cov + 0.1 * ortho
                    + 0.1 * (double)acc[A_L1] + 0.1 * sqrt((double)acc[A_L2SQ]);
        out[0] = (float)loss;
    }
}

extern "C" void kernel_launch(void* const* d_in, const int* in_sizes, int n_in,
                              void* d_out, int out_size, void* d_ws, size_t ws_size,
                              hipStream_t stream) {
    (void)in_sizes; (void)n_in; (void)out_size; (void)ws_size;
    const float* output_lp = (const float*)d_in[0];
    const int*   target    = (const int*)d_in[1];
    const float* W         = (const float*)d_in[2];
    const float* F         = (const float*)d_in[3];

    char*     ws     = (char*)d_ws;
    float*    acc    = (float*)(ws + ACC_OFF);
    unsigned* ticket = (unsigned*)(ws + TICKET_OFF);
    float*    colsum = (float*)(ws + COLSUM_OFF);
    short*    Fbt    = (short*)(ws + FBT_OFF);
    short*    Wb     = (short*)(ws + WB_OFF);
    float*    G      = (float*)(ws + G_OFF);
    float*    H      = (float*)(ws + H_OFF);

    // acc + ticket + colsum must be zero BEFORE K1's atomics (ws poisoned before launch).
    // G/H are zeroed by K1 roles (only touched by K2 atomics — cross-launch ordering).
    hipMemsetAsync(ws, 0, 8192, stream);

    prep_kernel<<<1028, 256, 0, stream>>>(output_lp, target, W, F, Wb, Fbt, colsum, acc, G, H);
    main_kernel<<<2048, 256, 0, stream>>>(Fbt, G, Wb, H, F, colsum, acc);
    fro_final_kernel<<<91, 256, 0, stream>>>(G, H, acc, colsum, ticket, (float*)d_out);
}

// Round 4
// 294.941 us; speedup vs baseline: 1.0493x; 1.0076x over previous
//
#include <hip/hip_runtime.h>
#include <stdint.h>
#include <stddef.h>

#define B_N    16384
#define NCLS_N 1000
#define C_N    1280

// workspace layout (bytes). Required ws_size >= ~52.8 MB.
#define ACC_OFF    0ULL
#define TICKET_OFF 64ULL
#define COLSUM_OFF 128ULL
#define FBT_OFF    8192ULL                         // bf16 panel [512kc][4kj][1280][8]
#define WB_OFF     41951232ULL                     // bf16 panel [40kc][4kj][1024][8] (rows >=1000 zero)
#define G_OFF      44572672ULL                     // fp32 [1280][1280]
#define H_OFF      51126272ULL                     // fp32 [1024][1024]

enum { A_NLL = 0, A_KL = 1, A_L1 = 2, A_L2SQ = 3, A_SUMSQF = 4, A_FMU2 = 5, A_GFRO = 6, A_HFRO = 7 };

typedef short s16x8 __attribute__((ext_vector_type(8)));
typedef float f32x4 __attribute__((ext_vector_type(4)));

__device__ __forceinline__ unsigned short f2bf(float f) {
    union { float f; unsigned int u; } v; v.f = f;
    unsigned int u = v.u;
    u += 0x7fffu + ((u >> 16) & 1u);   // RNE
    return (unsigned short)(u >> 16);
}

__device__ __forceinline__ float wave_red(float v) {
#pragma unroll
    for (int o = 32; o; o >>= 1) v += __shfl_down(v, o, 64);
    return v;
}

// ================= role bodies =================

// ---------------- NLL gather ----------------
__device__ __forceinline__ void nll_body(const float* __restrict__ lp,
                                         const int* __restrict__ tgt,
                                         float* __restrict__ acc, int bidx) {
    int b = bidx * 256 + threadIdx.x;
    int t = tgt[b];
    float v = lp[(size_t)b * NCLS_N + t];
    v = wave_red(v);
    __shared__ float sm_nll[4];
    int wid = threadIdx.x >> 6, lane = threadIdx.x & 63;
    if (lane == 0) sm_nll[wid] = v;
    __syncthreads();
    if (threadIdx.x == 0) atomicAdd(&acc[A_NLL], sm_nll[0] + sm_nll[1] + sm_nll[2] + sm_nll[3]);
}

// ---------------- weights: bf16 panel cast (padded to 1024 rows) + L1 + L2sq ----------------
__device__ __forceinline__ void wpass_body(const float* __restrict__ W,
                                           short* __restrict__ Wb,
                                           float* __restrict__ acc, int idx) {
    int bx = idx & 3;                           // 0..3 row-group
    int kc = idx >> 2;                          // 0..39
    int m = bx * 256 + threadIdx.x;             // 0..1023
    bool live = (m < NCLS_N);
    const float4* Wr = (const float4*)(W + (size_t)m * C_N);
    float l1 = 0.f, l2 = 0.f;
#pragma unroll
    for (int kj = 0; kj < 4; kj++) {
        s16x8 pk = { 0, 0, 0, 0, 0, 0, 0, 0 };
        if (live) {
            float4 a = Wr[kc * 8 + kj * 2];
            float4 b = Wr[kc * 8 + kj * 2 + 1];
            l1 += fabsf(a.x) + fabsf(a.y) + fabsf(a.z) + fabsf(a.w)
                + fabsf(b.x) + fabsf(b.y) + fabsf(b.z) + fabsf(b.w);
            l2 += a.x * a.x + a.y * a.y + a.z * a.z + a.w * a.w
                + b.x * b.x + b.y * b.y + b.z * b.z + b.w * b.w;
            pk[0] = (short)f2bf(a.x); pk[1] = (short)f2bf(a.y);
            pk[2] = (short)f2bf(a.z); pk[3] = (short)f2bf(a.w);
            pk[4] = (short)f2bf(b.x); pk[5] = (short)f2bf(b.y);
            pk[6] = (short)f2bf(b.z); pk[7] = (short)f2bf(b.w);
        }
        *(s16x8*)(Wb + ((size_t)(kc * 4 + kj) * 1024 + m) * 8) = pk;
    }
    l1 = wave_red(l1);
    l2 = wave_red(l2);
    __shared__ float sm_w[4][2];
    int wid = threadIdx.x >> 6, lane = threadIdx.x & 63;
    if (lane == 0) { sm_w[wid][0] = l1; sm_w[wid][1] = l2; }
    __syncthreads();
    if (threadIdx.x == 0) {
        atomicAdd(&acc[A_L1],   sm_w[0][0] + sm_w[1][0] + sm_w[2][0] + sm_w[3][0]);
        atomicAdd(&acc[A_L2SQ], sm_w[0][1] + sm_w[1][1] + sm_w[2][1] + sm_w[3][1]);
    }
}

// ---------------- features: bf16 panel transpose + column sums + sum of squares ----------------
__device__ __forceinline__ void fpass_body(const float* __restrict__ F,
                                           short* __restrict__ Fbt,
                                           float* __restrict__ colsum,
                                           float* __restrict__ acc, int idx) {
    int bx = idx % 5;                           // 0..4 column group
    int by = idx / 5;                           // 0..127
    int c = bx * 256 + threadIdx.x;             // 0..1279
    int kc0 = by * 4;                           // 4 chunks of 32 k per block
    float cs = 0.f, sq = 0.f;
    for (int ch = 0; ch < 4; ch++) {
        int kc = kc0 + ch;
        int kbase = kc * 32;
#pragma unroll
        for (int kj = 0; kj < 4; kj++) {
            float v[8];
#pragma unroll
            for (int e = 0; e < 8; e++) v[e] = F[(size_t)(kbase + kj * 8 + e) * C_N + c];
            s16x8 pk;
#pragma unroll
            for (int e = 0; e < 8; e++) {
                cs += v[e];
                sq += v[e] * v[e];
                pk[e] = (short)f2bf(v[e]);
            }
            *(s16x8*)(Fbt + ((size_t)(kc * 4 + kj) * C_N + c) * 8) = pk;
        }
    }
    atomicAdd(&colsum[c], cs);
    sq = wave_red(sq);
    __shared__ float sm_f[4];
    int wid = threadIdx.x >> 6, lane = threadIdx.x & 63;
    if (lane == 0) sm_f[wid] = sq;
    __syncthreads();
    if (threadIdx.x == 0) atomicAdd(&acc[A_SUMSQF], sm_f[0] + sm_f[1] + sm_f[2] + sm_f[3]);
}

// ---------------- per-row KL term (||F mu||^2 moved to fro via mu^T G mu) ----------------
// No colsum dependency anymore -> lives in prep; 3 wave_reds instead of 4, no M loads.
__device__ __forceinline__ void klpass_body(const float* __restrict__ F,
                                            float* __restrict__ acc, int idx) {
    int wid = threadIdx.x >> 6, lane = threadIdx.x & 63;
    int gwave = idx * 4 + wid;                   // 0..4095
    float kl_acc = 0.f;
    for (int b = gwave; b < B_N; b += 4096) {
        const float4* Fr = (const float4*)(F + (size_t)b * C_N);
        float s = 0.f, tt = 0.f, sf = 0.f;
#pragma unroll
        for (int i = 0; i < 5; i++) {
            float4 f = Fr[lane + 64 * i];
            float e0 = __expf(f.x), e1 = __expf(f.y), e2 = __expf(f.z), e3 = __expf(f.w);
            s  += e0 + e1 + e2 + e3;
            tt += e0 * f.x + e1 * f.y + e2 * f.z + e3 * f.w;
            sf += f.x + f.y + f.z + f.w;
        }
        s = wave_red(s); tt = wave_red(tt); sf = wave_red(sf);
        if (lane == 0) kl_acc += (float)C_N * (tt / s) - sf;
    }
    __shared__ float sm_kl[4];
    if (lane == 0) sm_kl[wid] = kl_acc;
    __syncthreads();
    if (threadIdx.x == 0)
        atomicAdd(&acc[A_KL], sm_kl[0] + sm_kl[1] + sm_kl[2] + sm_kl[3]);
}

// ---------------- bf16 Gram: S += X X^T, 2-phase pipelined, XCD-local K-chunks ----------------
// X: panel layout [kc][kj][Mp][8] bf16 (k = kc*32 + kj*8 + e).
// 128x128 tile, 4 waves (2x2 of 64x64), BK=32, 16x16x32 MFMA.
// LDS [128 rows][4 slots][8] with XOR swizzle: slot s at row r holds kj = s ^ (r&3).
// FOUR distinct static buffers and NO runtime buffer select (B always staged, even for
// diagonal tiles, where its loads are L2-hits): every LDS access has compile-time buffer
// identity, so the memory legalizer cannot pessimistically vmcnt(0)-drain the in-flight
// next-step global_load_lds before the current step's ds_reads.
// ONE barrier per K-step: stage(next) -> ds_read+MFMA(cur) -> __syncthreads (drains vmcnt).
// Requires nt = chunkK/32 EVEN (G: 32, H: 10).
__device__ __forceinline__ void gram_body(const short* __restrict__ X,
                                          float* __restrict__ S,
                                          int Mp, int T, int tile, int kc_blk, int chunkK) {
    __shared__ __align__(16) short A0[128 * 32];
    __shared__ __align__(16) short A1[128 * 32];
    __shared__ __align__(16) short B0[128 * 32];
    __shared__ __align__(16) short B1[128 * 32];
    int tid = threadIdx.x;
    int bi = 0, rem = tile;
    while (rem >= T - bi) { rem -= T - bi; bi++; }
    int bj = bi + rem;
    int i0 = bi * 128, j0 = bj * 128;

    int wave = tid >> 6, lane = tid & 63;
    int wm = wave >> 1, wn = wave & 1;
    int quad = lane >> 4, l16 = lane & 15;

    // per-thread staging constants: thread covers g0 = tid, g1 = 256+tid
    const size_t kstep = (size_t)Mp * 32;       // shorts per kc step (4*Mp*8)
    const short *pa0, *pa1, *pb0, *pb1;
    int lo0 = tid * 8, lo1 = (256 + tid) * 8;
    {
        int g0 = tid, g1 = 256 + tid;
        int r0 = g0 >> 2, r1 = g1 >> 2;
        int kj0 = (g0 & 3) ^ (r0 & 3), kj1 = (g1 & 3) ^ (r1 & 3);
        size_t base = (size_t)(kc_blk * chunkK >> 5) * kstep;
        pa0 = X + base + ((size_t)kj0 * Mp + i0 + r0) * 8;
        pa1 = X + base + ((size_t)kj1 * Mp + i0 + r1) * 8;
        pb0 = X + base + ((size_t)kj0 * Mp + j0 + r0) * 8;
        pb1 = X + base + ((size_t)kj1 * Mp + j0 + r1) * 8;
    }

    f32x4 acc[4][4];
#pragma unroll
    for (int i = 0; i < 4; i++)
#pragma unroll
        for (int j = 0; j < 4; j++) acc[i][j] = { 0.f, 0.f, 0.f, 0.f };

    auto stage = [&](short* Ad, short* Bd) {
        __builtin_amdgcn_global_load_lds((const __attribute__((address_space(1))) unsigned int*)pa0,
                                         (__attribute__((address_space(3))) unsigned int*)(Ad + lo0), 16, 0, 0);
        __builtin_amdgcn_global_load_lds((const __attribute__((address_space(1))) unsigned int*)pa1,
                                         (__attribute__((address_space(3))) unsigned int*)(Ad + lo1), 16, 0, 0);
        __builtin_amdgcn_global_load_lds((const __attribute__((address_space(1))) unsigned int*)pb0,
                                         (__attribute__((address_space(3))) unsigned int*)(Bd + lo0), 16, 0, 0);
        __builtin_amdgcn_global_load_lds((const __attribute__((address_space(1))) unsigned int*)pb1,
                                         (__attribute__((address_space(3))) unsigned int*)(Bd + lo1), 16, 0, 0);
        pa0 += kstep; pa1 += kstep; pb0 += kstep; pb1 += kstep;
    };

    auto compute = [&](const short* Ab, const short* Bb) {
        s16x8 af[4], bfr[4];
#pragma unroll
        for (int f = 0; f < 4; f++) {
            int mrow = wm * 64 + f * 16 + l16;
            af[f] = *(const s16x8*)(Ab + mrow * 32 + (quad ^ (mrow & 3)) * 8);
            int nrow = wn * 64 + f * 16 + l16;
            bfr[f] = *(const s16x8*)(Bb + nrow * 32 + (quad ^ (nrow & 3)) * 8);
        }
        __builtin_amdgcn_s_setprio(1);
#pragma unroll
        for (int i = 0; i < 4; i++)
#pragma unroll
            for (int j = 0; j < 4; j++)
                acc[i][j] = __builtin_amdgcn_mfma_f32_16x16x32_bf16(af[i], bfr[j], acc[i][j], 0, 0, 0);
        __builtin_amdgcn_s_setprio(0);
    };

    int nt = chunkK >> 5;                        // even by construction
    stage(A0, B0);                               // prologue: k-step 0
    __syncthreads();                             // vmcnt(0) drain + barrier
    for (int t = 0; t < nt; t += 2) {
        stage(A1, B1);                           // k-step t+1 in flight under compute
        compute(A0, B0);
        __syncthreads();                         // drains vmcnt -> A1/B1 ready; A0/B0 reads done
        if (t + 2 < nt) stage(A0, B0);           // k-step t+2
        compute(A1, B1);
        __syncthreads();
    }

#pragma unroll
    for (int i = 0; i < 4; i++)
#pragma unroll
        for (int j = 0; j < 4; j++)
#pragma unroll
            for (int r = 0; r < 4; r++) {
                int grow = i0 + wm * 64 + i * 16 + quad * 4 + r;
                int gcol = j0 + wn * 64 + j * 16 + l16;
                atomicAdd(&S[(size_t)grow * Mp + gcol], acc[i][j][r]);
            }
}

// ---------------- Frobenius^2 (+ optional mu^T S mu) over triangular tiles ----------------
// off-diag tiles weighted 2x (symmetry), valid for both quadratic forms.
__device__ __forceinline__ void fro_tile(const float* __restrict__ S,
                                         const float* __restrict__ mu_src,  // colsum or nullptr
                                         int Mp, int T, int tile,
                                         float* __restrict__ slotF,
                                         float* __restrict__ slotQ) {
    int bi = 0, rem = tile;
    while (rem >= T - bi) { rem -= T - bi; bi++; }
    int bj = bi + rem;
    size_t base = (size_t)bi * 128 * Mp + (size_t)bj * 128;
    const float invB = 1.f / (float)B_N;
    float sum = 0.f, q = 0.f;
    for (int l = threadIdx.x * 4; l < 128 * 128; l += 1024) {
        int row = l >> 7, col = l & 127;
        float4 v = *(const float4*)(S + base + (size_t)row * Mp + col);
        sum += v.x * v.x + v.y * v.y + v.z * v.z + v.w * v.w;
        if (mu_src) {
            float mr = mu_src[bi * 128 + row] * invB;
            float4 mc = *(const float4*)(mu_src + bj * 128 + col);
            q += mr * (v.x * mc.x + v.y * mc.y + v.z * mc.z + v.w * mc.w) * invB;
        }
    }
    sum = wave_red(sum);
    q = wave_red(q);
    __shared__ float sm_fro[4][2];
    int wid = threadIdx.x >> 6, lane = threadIdx.x & 63;
    if (lane == 0) { sm_fro[wid][0] = sum; sm_fro[wid][1] = q; }
    __syncthreads();
    if (threadIdx.x == 0) {
        float w = (bi == bj) ? 1.f : 2.f;
        atomicAdd(slotF, w * (sm_fro[0][0] + sm_fro[1][0] + sm_fro[2][0] + sm_fro[3][0]));
        if (mu_src)
            atomicAdd(slotQ, w * (sm_fro[0][1] + sm_fro[1][1] + sm_fro[2][1] + sm_fro[3][1]));
    }
}

// ================= fused kernels =================

// K1: blocks [0,1024) klpass | [1024,1664) fpass | [1664,1824) wpass
//     | [1824,1888) nll | [1888,1988) zero G | [1988,2052) zero H.
// klpass (VALU/exp/shuffle latency-chains) overlaps the streaming roles.
__global__ __launch_bounds__(256) void prep_kernel(const float* __restrict__ lp,
                                                   const int* __restrict__ tgt,
                                                   const float* __restrict__ W,
                                                   const float* __restrict__ F,
                                                   short* __restrict__ Wb,
                                                   short* __restrict__ Fbt,
                                                   float* __restrict__ colsum,
                                                   float* __restrict__ acc,
                                                   float* __restrict__ G,
                                                   float* __restrict__ H) {
    int b = blockIdx.x;
    if (b < 1024) {
        klpass_body(F, acc, b);
    } else if (b < 1664) {
        fpass_body(F, Fbt, colsum, acc, b - 1024);
    } else if (b < 1824) {
        wpass_body(W, Wb, acc, b - 1664);
    } else if (b < 1888) {
        nll_body(lp, tgt, acc, b - 1824);
    } else if (b < 1988) {
        float4* p = (float4*)G + (size_t)(b - 1888) * 4096;   // 100 * 64KB = 6.5536 MB exact
        float4 z = { 0.f, 0.f, 0.f, 0.f };
        for (int i = threadIdx.x; i < 4096; i += 256) p[i] = z;
    } else {
        float4* p = (float4*)H + (size_t)(b - 1988) * 4096;   // 64 * 64KB = 4.1943 MB exact
        float4 z = { 0.f, 0.f, 0.f, 0.f };
        for (int i = threadIdx.x; i < 4096; i += 256) p[i] = z;
    }
}

// K2: pure gram. blocks [0,880) gram G | [880,1024) gram H.
// kc-minor decode: XCD(=blockIdx%8) owns fixed K-regions of the panel (R3: FETCH 202->78MB).
__global__ __launch_bounds__(256) void main_kernel(const short* __restrict__ Fbt,
                                                   float* __restrict__ G,
                                                   const short* __restrict__ Wb,
                                                   float* __restrict__ H) {
    int b = blockIdx.x;
    if (b < 880) {
        gram_body(Fbt, G, C_N, 10, b >> 4, b & 15, 1024);        // Mp=1280, T=10, 55 tiles x 16 kc (nt=32)
    } else {
        int l = b - 880;                                         // 880 % 8 == 0: local%8 == blockIdx%8
        gram_body(Wb, H, 1024, 8, l >> 2, l & 3, 320);           // Mp=1024, T=8, 36 tiles x 4 kc (nt=10)
    }
}

// K3: Frobenius reductions (+ mu^T G mu into A_FMU2) + last-block final combine.
// blocks: [0,55) G | [55,91) H.
__global__ __launch_bounds__(256) void fro_final_kernel(const float* __restrict__ G,
                                                        const float* __restrict__ H,
                                                        float* __restrict__ acc,
                                                        const float* __restrict__ colsum,
                                                        unsigned* __restrict__ ticket,
                                                        float* __restrict__ out) {
    int b = blockIdx.x;
    if (b < 55) fro_tile(G, colsum, C_N, 10, b, acc + A_GFRO, acc + A_FMU2);
    else        fro_tile(H, nullptr, 1024, 8, b - 55, acc + A_HFRO, nullptr);

    __shared__ int amlast;
    if (threadIdx.x == 0) {
        __threadfence();                               // order my fro atomicAdds before ticket
        unsigned prev = atomicAdd(ticket, 1u);
        amlast = (prev == 90u);
    }
    __syncthreads();
    if (!amlast) return;
    __threadfence();                                   // acquire side

    // final combine (winner block only). colsum & prep-acc slots are prior-dispatch
    // (kernel-boundary coherent); A_GFRO/A_HFRO/A_FMU2 are same-dispatch -> atomic read.
    float s = 0.f;
    for (int c = threadIdx.x; c < C_N; c += 256) { float v = colsum[c]; s += v * v; }
    s = wave_red(s);
    __shared__ float sm[4];
    int wid = threadIdx.x >> 6, lane = threadIdx.x & 63;
    if (lane == 0) sm[wid] = s;
    __syncthreads();
    if (threadIdx.x == 0) {
        double musq_raw = (double)(sm[0] + sm[1] + sm[2] + sm[3]);   // sum colsum^2 = B^2 * ||mu||^2
        double Bd = (double)B_N;
        double gfro = (double)atomicAdd(&acc[A_GFRO], 0.0f);
        double hfro = (double)atomicAdd(&acc[A_HFRO], 0.0f);
        double fmu2 = (double)atomicAdd(&acc[A_FMU2], 0.0f);         // = mu^T G mu = sum_b (F mu)_b^2
        double nll = -((double)acc[A_NLL] / Bd);
        double kl  = (double)acc[A_KL] / Bd;
        double trG = (double)acc[A_SUMSQF];
        double musq = musq_raw / (Bd * Bd);
        double cov = gfro / (Bd * Bd)
                   - (2.0 / Bd) * fmu2
                   + musq * musq
                   - 2.0 * (trG / Bd - musq)
                   + (double)C_N;
        double ortho = hfro - 2.0 * (double)acc[A_L2SQ] + (double)NCLS_N;
        double loss = 1.0 * nll + 0.2 * kl + 0.2 * cov + 0.1 * ortho
                    + 0.1 * (double)acc[A_L1] + 0.1 * sqrt((double)acc[A_L2SQ]);
        out[0] = (float)loss;
    }
}

extern "C" void kernel_launch(void* const* d_in, const int* in_sizes, int n_in,
                              void* d_out, int out_size, void* d_ws, size_t ws_size,
                              hipStream_t stream) {
    (void)in_sizes; (void)n_in; (void)out_size; (void)ws_size;
    const float* output_lp = (const float*)d_in[0];
    const int*   target    = (const int*)d_in[1];
    const float* W         = (const float*)d_in[2];
    const float* F         = (const float*)d_in[3];

    char*     ws     = (char*)d_ws;
    float*    acc    = (float*)(ws + ACC_OFF);
    unsigned* ticket = (unsigned*)(ws + TICKET_OFF);
    float*    colsum = (float*)(ws + COLSUM_OFF);
    short*    Fbt    = (short*)(ws + FBT_OFF);
    short*    Wb     = (short*)(ws + WB_OFF);
    float*    G      = (float*)(ws + G_OFF);
    float*    H      = (float*)(ws + H_OFF);

    // acc + ticket + colsum must be zero BEFORE K1's atomics (ws poisoned before launch).
    // G/H are zeroed by K1 roles (only touched by K2 atomics — cross-launch ordering).
    hipMemsetAsync(ws, 0, 8192, stream);

    prep_kernel<<<2052, 256, 0, stream>>>(output_lp, target, W, F, Wb, Fbt, colsum, acc, G, H);
    main_kernel<<<1024, 256, 0, stream>>>(Fbt, G, Wb, H);
    fro_final_kernel<<<91, 256, 0, stream>>>(G, H, acc, colsum, ticket, (float*)d_out);
}

// Round 6
// 268.461 us; speedup vs baseline: 1.1528x; 1.0986x over previous
//
#include <hip/hip_runtime.h>
#include <stdint.h>
#include <stddef.h>

#define B_N    16384
#define NCLS_N 1000
#define C_N    1280

// workspace layout (bytes).
// common:  [0,128) acc | [64) ticket | [128,5248) colsum | FBT 41.94MB | WB 2.62MB
// atomic path (ws >= ~52.8MB):  G fp32[1280][1280] @ G_OFF, H fp32[1024][1024] @ H_OFF
// partial path (ws >= ~111.7MB): Gp fp32[16][55][128][128] @ G_OFF (57.7MB),
//                                Hp fp32[4][36][128][128] @ HP_OFF (9.4MB)
#define ACC_OFF    0ULL
#define TICKET_OFF 64ULL
#define COLSUM_OFF 128ULL
#define FBT_OFF    8192ULL                         // bf16 panel [512kc][4kj][1280][8]
#define WB_OFF     41951232ULL                     // bf16 panel [40kc][4kj][1024][8] (rows >=1000 zero)
#define G_OFF      44572672ULL                     // atomic: fp32 [1280][1280] / partial: Gp base
#define H_OFF      51126272ULL                     // atomic: fp32 [1024][1024]
#define HP_OFF     102244352ULL                    // partial: Hp base
#define WS_PART_NEED 111681536ULL

enum { A_NLL = 0, A_KL = 1, A_L1 = 2, A_L2SQ = 3, A_SUMSQF = 4, A_FMU2 = 5, A_GFRO = 6, A_HFRO = 7 };

typedef short s16x8 __attribute__((ext_vector_type(8)));
typedef float f32x4 __attribute__((ext_vector_type(4)));

__device__ __forceinline__ unsigned short f2bf(float f) {
    union { float f; unsigned int u; } v; v.f = f;
    unsigned int u = v.u;
    u += 0x7fffu + ((u >> 16) & 1u);   // RNE
    return (unsigned short)(u >> 16);
}

__device__ __forceinline__ float wave_red(float v) {
#pragma unroll
    for (int o = 32; o; o >>= 1) v += __shfl_down(v, o, 64);
    return v;
}

// ================= role bodies =================

// ---------------- NLL gather ----------------
__device__ __forceinline__ void nll_body(const float* __restrict__ lp,
                                         const int* __restrict__ tgt,
                                         float* __restrict__ acc, int bidx) {
    int b = bidx * 256 + threadIdx.x;
    int t = tgt[b];
    float v = lp[(size_t)b * NCLS_N + t];
    v = wave_red(v);
    __shared__ float sm_nll[4];
    int wid = threadIdx.x >> 6, lane = threadIdx.x & 63;
    if (lane == 0) sm_nll[wid] = v;
    __syncthreads();
    if (threadIdx.x == 0) atomicAdd(&acc[A_NLL], sm_nll[0] + sm_nll[1] + sm_nll[2] + sm_nll[3]);
}

// ---------------- weights: bf16 panel cast (padded to 1024 rows) + L1 + L2sq ----------------
__device__ __forceinline__ void wpass_body(const float* __restrict__ W,
                                           short* __restrict__ Wb,
                                           float* __restrict__ acc, int idx) {
    int bx = idx & 3;                           // 0..3 row-group
    int kc = idx >> 2;                          // 0..39
    int m = bx * 256 + threadIdx.x;             // 0..1023
    bool live = (m < NCLS_N);
    const float4* Wr = (const float4*)(W + (size_t)m * C_N);
    float l1 = 0.f, l2 = 0.f;
#pragma unroll
    for (int kj = 0; kj < 4; kj++) {
        s16x8 pk = { 0, 0, 0, 0, 0, 0, 0, 0 };
        if (live) {
            float4 a = Wr[kc * 8 + kj * 2];
            float4 b = Wr[kc * 8 + kj * 2 + 1];
            l1 += fabsf(a.x) + fabsf(a.y) + fabsf(a.z) + fabsf(a.w)
                + fabsf(b.x) + fabsf(b.y) + fabsf(b.z) + fabsf(b.w);
            l2 += a.x * a.x + a.y * a.y + a.z * a.z + a.w * a.w
                + b.x * b.x + b.y * b.y + b.z * b.z + b.w * b.w;
            pk[0] = (short)f2bf(a.x); pk[1] = (short)f2bf(a.y);
            pk[2] = (short)f2bf(a.z); pk[3] = (short)f2bf(a.w);
            pk[4] = (short)f2bf(b.x); pk[5] = (short)f2bf(b.y);
            pk[6] = (short)f2bf(b.z); pk[7] = (short)f2bf(b.w);
        }
        *(s16x8*)(Wb + ((size_t)(kc * 4 + kj) * 1024 + m) * 8) = pk;
    }
    l1 = wave_red(l1);
    l2 = wave_red(l2);
    __shared__ float sm_w[4][2];
    int wid = threadIdx.x >> 6, lane = threadIdx.x & 63;
    if (lane == 0) { sm_w[wid][0] = l1; sm_w[wid][1] = l2; }
    __syncthreads();
    if (threadIdx.x == 0) {
        atomicAdd(&acc[A_L1],   sm_w[0][0] + sm_w[1][0] + sm_w[2][0] + sm_w[3][0]);
        atomicAdd(&acc[A_L2SQ], sm_w[0][1] + sm_w[1][1] + sm_w[2][1] + sm_w[3][1]);
    }
}

// ---------------- features: bf16 panel transpose + column sums + sum of squares ----------------
__device__ __forceinline__ void fpass_body(const float* __restrict__ F,
                                           short* __restrict__ Fbt,
                                           float* __restrict__ colsum,
                                           float* __restrict__ acc, int idx) {
    int bx = idx % 5;                           // 0..4 column group
    int by = idx / 5;                           // 0..127
    int c = bx * 256 + threadIdx.x;             // 0..1279
    int kc0 = by * 4;                           // 4 chunks of 32 k per block
    float cs = 0.f, sq = 0.f;
    for (int ch = 0; ch < 4; ch++) {
        int kc = kc0 + ch;
        int kbase = kc * 32;
#pragma unroll
        for (int kj = 0; kj < 4; kj++) {
            float v[8];
#pragma unroll
            for (int e = 0; e < 8; e++) v[e] = F[(size_t)(kbase + kj * 8 + e) * C_N + c];
            s16x8 pk;
#pragma unroll
            for (int e = 0; e < 8; e++) {
                cs += v[e];
                sq += v[e] * v[e];
                pk[e] = (short)f2bf(v[e]);
            }
            *(s16x8*)(Fbt + ((size_t)(kc * 4 + kj) * C_N + c) * 8) = pk;
        }
    }
    atomicAdd(&colsum[c], cs);
    sq = wave_red(sq);
    __shared__ float sm_f[4];
    int wid = threadIdx.x >> 6, lane = threadIdx.x & 63;
    if (lane == 0) sm_f[wid] = sq;
    __syncthreads();
    if (threadIdx.x == 0) atomicAdd(&acc[A_SUMSQF], sm_f[0] + sm_f[1] + sm_f[2] + sm_f[3]);
}

// ---------------- per-row KL term ----------------
// kl_row = C*(tt/s) - sf; Sum_rows sf == Sum(colsum), recovered in final -> only 2 wave_reds.
__device__ __forceinline__ void klpass_body(const float* __restrict__ F,
                                            float* __restrict__ acc, int idx) {
    int wid = threadIdx.x >> 6, lane = threadIdx.x & 63;
    int gwave = idx * 4 + wid;                   // 0..4095
    float kl_acc = 0.f;
    for (int b = gwave; b < B_N; b += 4096) {
        const float4* Fr = (const float4*)(F + (size_t)b * C_N);
        float s = 0.f, tt = 0.f;
#pragma unroll
        for (int i = 0; i < 5; i++) {
            float4 f = Fr[lane + 64 * i];
            float e0 = __expf(f.x), e1 = __expf(f.y), e2 = __expf(f.z), e3 = __expf(f.w);
            s  += e0 + e1 + e2 + e3;
            tt += e0 * f.x + e1 * f.y + e2 * f.z + e3 * f.w;
        }
        s = wave_red(s); tt = wave_red(tt);
        if (lane == 0) kl_acc += (float)C_N * (tt / s);
    }
    __shared__ float sm_kl[4];
    if (lane == 0) sm_kl[wid] = kl_acc;
    __syncthreads();
    if (threadIdx.x == 0)
        atomicAdd(&acc[A_KL], sm_kl[0] + sm_kl[1] + sm_kl[2] + sm_kl[3]);
}

// ---------------- bf16 Gram: S += X X^T, 2-phase pipelined, XCD-local K-chunks ----------------
// X: panel layout [kc][kj][Mp][8] bf16 (k = kc*32 + kj*8 + e).
// 128x128 tile, 4 waves (2x2 of 64x64), BK=32, 16x16x32 MFMA.
// LDS [128 rows][4 slots][8] with XOR swizzle: slot s at row r holds kj = s ^ (r&3).
// FOUR distinct static buffers, compile-time buffer identity (NoAlias for the legalizer).
// ONE barrier per K-step: stage(next) -> ds_read+MFMA(cur) -> __syncthreads.
// nt EVEN required.
// Epilogue: PART -> plain stores into private partial slot [kc_blk][tile][128][128]
//           (R4 diagnosis: 16.8M simultaneous f32 atomics = ~60us L2-RMW burst);
//           !PART -> atomicAdd into the full matrix (ws too small for partials).
template<bool PART>
__device__ __forceinline__ void gram_body(const short* __restrict__ X,
                                          float* __restrict__ S,
                                          int Mp, int T, int ntri,
                                          int tile, int kc_blk, int k0step, int nt) {
    __shared__ __align__(16) short A0[128 * 32];
    __shared__ __align__(16) short A1[128 * 32];
    __shared__ __align__(16) short B0[128 * 32];
    __shared__ __align__(16) short B1[128 * 32];
    int tid = threadIdx.x;
    int bi = 0, rem = tile;
    while (rem >= T - bi) { rem -= T - bi; bi++; }
    int bj = bi + rem;
    int i0 = bi * 128, j0 = bj * 128;

    int wave = tid >> 6, lane = tid & 63;
    int wm = wave >> 1, wn = wave & 1;
    int quad = lane >> 4, l16 = lane & 15;

    const size_t kstep = (size_t)Mp * 32;       // shorts per 32-k step
    const short *pa0, *pa1, *pb0, *pb1;
    int lo0 = tid * 8, lo1 = (256 + tid) * 8;
    {
        int g0 = tid, g1 = 256 + tid;
        int r0 = g0 >> 2, r1 = g1 >> 2;
        int kj0 = (g0 & 3) ^ (r0 & 3), kj1 = (g1 & 3) ^ (r1 & 3);
        size_t base = (size_t)k0step * kstep;
        pa0 = X + base + ((size_t)kj0 * Mp + i0 + r0) * 8;
        pa1 = X + base + ((size_t)kj1 * Mp + i0 + r1) * 8;
        pb0 = X + base + ((size_t)kj0 * Mp + j0 + r0) * 8;
        pb1 = X + base + ((size_t)kj1 * Mp + j0 + r1) * 8;
    }

    f32x4 acc[4][4];
#pragma unroll
    for (int i = 0; i < 4; i++)
#pragma unroll
        for (int j = 0; j < 4; j++) acc[i][j] = { 0.f, 0.f, 0.f, 0.f };

    auto stage = [&](short* Ad, short* Bd) {
        __builtin_amdgcn_global_load_lds((const __attribute__((address_space(1))) unsigned int*)pa0,
                                         (__attribute__((address_space(3))) unsigned int*)(Ad + lo0), 16, 0, 0);
        __builtin_amdgcn_global_load_lds((const __attribute__((address_space(1))) unsigned int*)pa1,
                                         (__attribute__((address_space(3))) unsigned int*)(Ad + lo1), 16, 0, 0);
        __builtin_amdgcn_global_load_lds((const __attribute__((address_space(1))) unsigned int*)pb0,
                                         (__attribute__((address_space(3))) unsigned int*)(Bd + lo0), 16, 0, 0);
        __builtin_amdgcn_global_load_lds((const __attribute__((address_space(1))) unsigned int*)pb1,
                                         (__attribute__((address_space(3))) unsigned int*)(Bd + lo1), 16, 0, 0);
        pa0 += kstep; pa1 += kstep; pb0 += kstep; pb1 += kstep;
    };

    auto compute = [&](const short* Ab, const short* Bb) {
        s16x8 af[4], bfr[4];
#pragma unroll
        for (int f = 0; f < 4; f++) {
            int mrow = wm * 64 + f * 16 + l16;
            af[f] = *(const s16x8*)(Ab + mrow * 32 + (quad ^ (mrow & 3)) * 8);
            int nrow = wn * 64 + f * 16 + l16;
            bfr[f] = *(const s16x8*)(Bb + nrow * 32 + (quad ^ (nrow & 3)) * 8);
        }
        __builtin_amdgcn_s_setprio(1);
#pragma unroll
        for (int i = 0; i < 4; i++)
#pragma unroll
            for (int j = 0; j < 4; j++)
                acc[i][j] = __builtin_amdgcn_mfma_f32_16x16x32_bf16(af[i], bfr[j], acc[i][j], 0, 0, 0);
        __builtin_amdgcn_s_setprio(0);
    };

    stage(A0, B0);                               // prologue: k-step 0
    __syncthreads();                             // vmcnt(0) drain + barrier
    for (int t = 0; t < nt; t += 2) {
        stage(A1, B1);                           // k-step t+1 in flight under compute
        compute(A0, B0);
        __syncthreads();                         // drains vmcnt -> A1/B1 ready; A0/B0 reads done
        if (t + 2 < nt) stage(A0, B0);           // k-step t+2
        compute(A1, B1);
        __syncthreads();
    }

    if (PART) {
        float* Sp = S + (((size_t)kc_blk * ntri + tile) << 14);  // private [128][128] slot
#pragma unroll
        for (int i = 0; i < 4; i++)
#pragma unroll
            for (int j = 0; j < 4; j++)
#pragma unroll
                for (int r = 0; r < 4; r++) {
                    int lrow = wm * 64 + i * 16 + quad * 4 + r;
                    int lcol = wn * 64 + j * 16 + l16;
                    Sp[lrow * 128 + lcol] = acc[i][j][r];
                }
    } else {
#pragma unroll
        for (int i = 0; i < 4; i++)
#pragma unroll
            for (int j = 0; j < 4; j++)
#pragma unroll
                for (int r = 0; r < 4; r++) {
                    int grow = i0 + wm * 64 + i * 16 + quad * 4 + r;
                    int gcol = j0 + wn * 64 + j * 16 + l16;
                    atomicAdd(&S[(size_t)grow * Mp + gcol], acc[i][j][r]);
                }
    }
}

// ---------------- Frobenius^2 (+ optional mu^T S mu) over triangular tiles ----------------
// off-diag tiles weighted 2x (symmetry). PART: element = sum of nks partials.
__device__ __forceinline__ void fro_tile_any(const float* __restrict__ S,
                                             const float* __restrict__ mu_src,
                                             int Mp, int T, int ntri, int tile, int nks, bool part,
                                             float* __restrict__ slotF,
                                             float* __restrict__ slotQ) {
    int bi = 0, rem = tile;
    while (rem >= T - bi) { rem -= T - bi; bi++; }
    int bj = bi + rem;
    size_t baseA = (size_t)bi * 128 * Mp + (size_t)bj * 128;       // atomic-path base
    const float* baseP = S + ((size_t)tile << 14);                 // partial-path base
    size_t pstride = (size_t)ntri << 14;
    const float invB = 1.f / (float)B_N;
    float sum = 0.f, q = 0.f;
    for (int l = threadIdx.x * 4; l < 128 * 128; l += 1024) {
        int row = l >> 7, col = l & 127;
        float4 v;
        if (part) {
            v = *(const float4*)(baseP + l);
            for (int ks = 1; ks < nks; ks++) {
                float4 u = *(const float4*)(baseP + (size_t)ks * pstride + l);
                v.x += u.x; v.y += u.y; v.z += u.z; v.w += u.w;
            }
        } else {
            v = *(const float4*)(S + baseA + (size_t)row * Mp + col);
        }
        sum += v.x * v.x + v.y * v.y + v.z * v.z + v.w * v.w;
        if (mu_src) {
            float mr = mu_src[bi * 128 + row] * invB;
            float4 mc = *(const float4*)(mu_src + bj * 128 + col);
            q += mr * (v.x * mc.x + v.y * mc.y + v.z * mc.z + v.w * mc.w) * invB;
        }
    }
    sum = wave_red(sum);
    q = wave_red(q);
    __shared__ float sm_fro[4][2];
    int wid = threadIdx.x >> 6, lane = threadIdx.x & 63;
    if (lane == 0) { sm_fro[wid][0] = sum; sm_fro[wid][1] = q; }
    __syncthreads();
    if (threadIdx.x == 0) {
        float w = (bi == bj) ? 1.f : 2.f;
        atomicAdd(slotF, w * (sm_fro[0][0] + sm_fro[1][0] + sm_fro[2][0] + sm_fro[3][0]));
        if (mu_src)
            atomicAdd(slotQ, w * (sm_fro[0][1] + sm_fro[1][1] + sm_fro[2][1] + sm_fro[3][1]));
    }
}

// ================= fused kernels =================

// K1: blocks [0,1024) klpass | [1024,1664) fpass | [1664,1824) wpass | [1824,1888) nll
//     | atomic path only: [1888,1988) zero G | [1988,2052) zero H.
__global__ __launch_bounds__(256) void prep_kernel(const float* __restrict__ lp,
                                                   const int* __restrict__ tgt,
                                                   const float* __restrict__ W,
                                                   const float* __restrict__ F,
                                                   short* __restrict__ Wb,
                                                   short* __restrict__ Fbt,
                                                   float* __restrict__ colsum,
                                                   float* __restrict__ acc,
                                                   float* __restrict__ G,
                                                   float* __restrict__ H) {
    int b = blockIdx.x;
    if (b < 1024) {
        klpass_body(F, acc, b);
    } else if (b < 1664) {
        fpass_body(F, Fbt, colsum, acc, b - 1024);
    } else if (b < 1824) {
        wpass_body(W, Wb, acc, b - 1664);
    } else if (b < 1888) {
        nll_body(lp, tgt, acc, b - 1824);
    } else if (b < 1988) {
        float4* p = (float4*)G + (size_t)(b - 1888) * 4096;   // 100 * 64KB = 6.5536 MB exact
        float4 z = { 0.f, 0.f, 0.f, 0.f };
        for (int i = threadIdx.x; i < 4096; i += 256) p[i] = z;
    } else {
        float4* p = (float4*)H + (size_t)(b - 1988) * 4096;   // 64 * 64KB = 4.1943 MB exact
        float4 z = { 0.f, 0.f, 0.f, 0.f };
        for (int i = threadIdx.x; i < 4096; i += 256) p[i] = z;
    }
}

// K2: pure gram. blocks [0,880) gram G (55 tiles x 16 kc) | [880,1024) gram H (36 x 4).
// kc-minor decode keeps XCD(=blockIdx%8) on fixed K-regions (R3: FETCH 202->78MB).
// Atomic path staggers nt per kc (XCD-paired to a constant 64-step/5.2MB L2 footprint)
// so the atomic epilogues spread across the compute window instead of one terminal burst.
template<bool PART>
__global__ __launch_bounds__(256) void main_kernel(const short* __restrict__ Fbt,
                                                   float* __restrict__ G,
                                                   const short* __restrict__ Wb,
                                                   float* __restrict__ H) {
    const int G_NT[16] = {18,22,26,30,20,24,28,32,46,42,38,34,44,40,36,32};
    const int G_K0[16] = {0,18,40,66,96,116,140,168,200,246,288,326,360,404,444,480};
    const int H_NT[4]  = {8,10,12,10};
    const int H_K0[4]  = {0,8,18,30};
    int b = blockIdx.x;
    if (b < 880) {
        int tile = b >> 4, kc = b & 15;
        int k0 = PART ? kc * 32 : G_K0[kc];
        int nt = PART ? 32      : G_NT[kc];
        gram_body<PART>(Fbt, G, C_N, 10, 55, tile, kc, k0, nt);
    } else {
        int l = b - 880;                         // 880 % 8 == 0: local%8 == blockIdx%8
        int tile = l >> 2, kc = l & 3;
        int k0 = PART ? kc * 10 : H_K0[kc];
        int nt = PART ? 10      : H_NT[kc];
        gram_body<PART>(Wb, H, 1024, 8, 36, tile, kc, k0, nt);
    }
}

// K3: Frobenius reductions (+ mu^T G mu into A_FMU2) + last-block final combine.
// blocks: [0,55) G | [55,91) H.
template<bool PART>
__global__ __launch_bounds__(256) void fro_final_kernel(const float* __restrict__ G,
                                                        const float* __restrict__ H,
                                                        float* __restrict__ acc,
                                                        const float* __restrict__ colsum,
                                                        unsigned* __restrict__ ticket,
                                                        float* __restrict__ out) {
    int b = blockIdx.x;
    if (b < 55) fro_tile_any(G, colsum, C_N, 10, 55, b, 16, PART, acc + A_GFRO, acc + A_FMU2);
    else        fro_tile_any(H, nullptr, 1024, 8, 36, b - 55, 4, PART, acc + A_HFRO, nullptr);

    __shared__ int amlast;
    if (threadIdx.x == 0) {
        __threadfence();                               // order my fro atomicAdds before ticket
        unsigned prev = atomicAdd(ticket, 1u);
        amlast = (prev == 90u);
    }
    __syncthreads();
    if (!amlast) return;
    __threadfence();                                   // acquire side

    // final combine (winner block only). colsum & prep-acc slots are prior-dispatch;
    // A_GFRO/A_HFRO/A_FMU2 are same-dispatch -> atomic read.
    float s = 0.f, s1 = 0.f;
    for (int c = threadIdx.x; c < C_N; c += 256) { float v = colsum[c]; s += v * v; s1 += v; }
    s = wave_red(s);
    s1 = wave_red(s1);
    __shared__ float sm[4][2];
    int wid = threadIdx.x >> 6, lane = threadIdx.x & 63;
    if (lane == 0) { sm[wid][0] = s; sm[wid][1] = s1; }
    __syncthreads();
    if (threadIdx.x == 0) {
        double musq_raw = (double)(sm[0][0] + sm[1][0] + sm[2][0] + sm[3][0]); // B^2*||mu||^2
        double sumF     = (double)(sm[0][1] + sm[1][1] + sm[2][1] + sm[3][1]); // Sum of all F
        double Bd = (double)B_N;
        double gfro = (double)atomicAdd(&acc[A_GFRO], 0.0f);
        double hfro = (double)atomicAdd(&acc[A_HFRO], 0.0f);
        double fmu2 = (double)atomicAdd(&acc[A_FMU2], 0.0f);         // mu^T G mu
        double nll = -((double)acc[A_NLL] / Bd);
        double kl  = ((double)acc[A_KL] - sumF) / Bd;                // klpass omits -sf now
        double trG = (double)acc[A_SUMSQF];
        double musq = musq_raw / (Bd * Bd);
        double cov = gfro / (Bd * Bd)
                   - (2.0 / Bd) * fmu2
                   + musq * musq
                   - 2.0 * (trG / Bd - musq)
                   + (double)C_N;
        double ortho = hfro - 2.0 * (double)acc[A_L2SQ] + (double)NCLS_N;
        double loss = 1.0 * nll + 0.2 * kl + 0.2 * cov + 0.1 * ortho
                    + 0.1 * (double)acc[A_L1] + 0.1 * sqrt((double)acc[A_L2SQ]);
        out[0] = (float)loss;
    }
}

extern "C" void kernel_launch(void* const* d_in, const int* in_sizes, int n_in,
                              void* d_out, int out_size, void* d_ws, size_t ws_size,
                              hipStream_t stream) {
    (void)in_sizes; (void)n_in; (void)out_size;
    const float* output_lp = (const float*)d_in[0];
    const int*   target    = (const int*)d_in[1];
    const float* W         = (const float*)d_in[2];
    const float* F         = (const float*)d_in[3];

    char*     ws     = (char*)d_ws;
    float*    acc    = (float*)(ws + ACC_OFF);
    unsigned* ticket = (unsigned*)(ws + TICKET_OFF);
    float*    colsum = (float*)(ws + COLSUM_OFF);
    short*    Fbt    = (short*)(ws + FBT_OFF);
    short*    Wb     = (short*)(ws + WB_OFF);

    bool part = (ws_size >= WS_PART_NEED);

    // acc + ticket + colsum must be zero BEFORE K1's atomics (ws poisoned before launch).
    hipMemsetAsync(ws, 0, 8192, stream);

    if (part) {
        // partial-store path: no G/H zero-init (every partial element is written).
        float* Gp = (float*)(ws + G_OFF);       // [16][55][128][128]
        float* Hp = (float*)(ws + HP_OFF);      // [4][36][128][128]
        prep_kernel<<<1888, 256, 0, stream>>>(output_lp, target, W, F, Wb, Fbt, colsum, acc, Gp, Hp);
        main_kernel<true><<<1024, 256, 0, stream>>>(Fbt, Gp, Wb, Hp);
        fro_final_kernel<true><<<91, 256, 0, stream>>>(Gp, Hp, acc, colsum, ticket, (float*)d_out);
    } else {
        float* G = (float*)(ws + G_OFF);        // [1280][1280]
        float* H = (float*)(ws + H_OFF);        // [1024][1024]
        prep_kernel<<<2052, 256, 0, stream>>>(output_lp, target, W, F, Wb, Fbt, colsum, acc, G, H);
        main_kernel<false><<<1024, 256, 0, stream>>>(Fbt, G, Wb, H);
        fro_final_kernel<false><<<91, 256, 0, stream>>>(G, H, acc, colsum, ticket, (float*)d_out);
    }
}

// Round 7
// 266.243 us; speedup vs baseline: 1.1624x; 1.0083x over previous
//
#include <hip/hip_runtime.h>
#include <stdint.h>
#include <stddef.h>

#define B_N    16384
#define NCLS_N 1000
#define C_N    1280

// workspace layout (bytes).
// common:  [0,128) acc | [64) ticket | [128,5248) colsum | FBT 41.94MB | WB 2.62MB
// atomic path (ws >= ~52.8MB):  G fp32[1280][1280] @ G_OFF, H fp32[1024][1024] @ H_OFF
// partial path (ws >= ~111.7MB): Gp fp32[16][55][128][128] @ G_OFF (57.7MB),
//                                Hp fp32[4][36][128][128] @ HP_OFF (9.4MB)
#define ACC_OFF    0ULL
#define TICKET_OFF 64ULL
#define COLSUM_OFF 128ULL
#define FBT_OFF    8192ULL                         // bf16 panel [512kc][4kj][1280][8]
#define WB_OFF     41951232ULL                     // bf16 panel [40kc][4kj][1024][8] (rows >=1000 zero)
#define G_OFF      44572672ULL                     // atomic: fp32 [1280][1280] / partial: Gp base
#define H_OFF      51126272ULL                     // atomic: fp32 [1024][1024]
#define HP_OFF     102244352ULL                    // partial: Hp base
#define WS_PART_NEED 111681536ULL

enum { A_NLL = 0, A_KL = 1, A_L1 = 2, A_L2SQ = 3, A_SUMSQF = 4, A_FMU2 = 5, A_GFRO = 6, A_HFRO = 7 };

typedef short s16x8 __attribute__((ext_vector_type(8)));
typedef float f32x4 __attribute__((ext_vector_type(4)));

__device__ __forceinline__ unsigned short f2bf(float f) {
    union { float f; unsigned int u; } v; v.f = f;
    unsigned int u = v.u;
    u += 0x7fffu + ((u >> 16) & 1u);   // RNE
    return (unsigned short)(u >> 16);
}

__device__ __forceinline__ float wave_red(float v) {
#pragma unroll
    for (int o = 32; o; o >>= 1) v += __shfl_down(v, o, 64);
    return v;
}

// ================= role bodies =================

// ---------------- NLL gather ----------------
__device__ __forceinline__ void nll_body(const float* __restrict__ lp,
                                         const int* __restrict__ tgt,
                                         float* __restrict__ acc, int bidx) {
    int b = bidx * 256 + threadIdx.x;
    int t = tgt[b];
    float v = lp[(size_t)b * NCLS_N + t];
    v = wave_red(v);
    __shared__ float sm_nll[4];
    int wid = threadIdx.x >> 6, lane = threadIdx.x & 63;
    if (lane == 0) sm_nll[wid] = v;
    __syncthreads();
    if (threadIdx.x == 0) atomicAdd(&acc[A_NLL], sm_nll[0] + sm_nll[1] + sm_nll[2] + sm_nll[3]);
}

// ---------------- weights: bf16 panel cast (padded to 1024 rows) + L1 + L2sq ----------------
__device__ __forceinline__ void wpass_body(const float* __restrict__ W,
                                           short* __restrict__ Wb,
                                           float* __restrict__ acc, int idx) {
    int bx = idx & 3;                           // 0..3 row-group
    int kc = idx >> 2;                          // 0..39
    int m = bx * 256 + threadIdx.x;             // 0..1023
    bool live = (m < NCLS_N);
    const float4* Wr = (const float4*)(W + (size_t)m * C_N);
    float l1 = 0.f, l2 = 0.f;
#pragma unroll
    for (int kj = 0; kj < 4; kj++) {
        s16x8 pk = { 0, 0, 0, 0, 0, 0, 0, 0 };
        if (live) {
            float4 a = Wr[kc * 8 + kj * 2];
            float4 b = Wr[kc * 8 + kj * 2 + 1];
            l1 += fabsf(a.x) + fabsf(a.y) + fabsf(a.z) + fabsf(a.w)
                + fabsf(b.x) + fabsf(b.y) + fabsf(b.z) + fabsf(b.w);
            l2 += a.x * a.x + a.y * a.y + a.z * a.z + a.w * a.w
                + b.x * b.x + b.y * b.y + b.z * b.z + b.w * b.w;
            pk[0] = (short)f2bf(a.x); pk[1] = (short)f2bf(a.y);
            pk[2] = (short)f2bf(a.z); pk[3] = (short)f2bf(a.w);
            pk[4] = (short)f2bf(b.x); pk[5] = (short)f2bf(b.y);
            pk[6] = (short)f2bf(b.z); pk[7] = (short)f2bf(b.w);
        }
        *(s16x8*)(Wb + ((size_t)(kc * 4 + kj) * 1024 + m) * 8) = pk;
    }
    l1 = wave_red(l1);
    l2 = wave_red(l2);
    __shared__ float sm_w[4][2];
    int wid = threadIdx.x >> 6, lane = threadIdx.x & 63;
    if (lane == 0) { sm_w[wid][0] = l1; sm_w[wid][1] = l2; }
    __syncthreads();
    if (threadIdx.x == 0) {
        atomicAdd(&acc[A_L1],   sm_w[0][0] + sm_w[1][0] + sm_w[2][0] + sm_w[3][0]);
        atomicAdd(&acc[A_L2SQ], sm_w[0][1] + sm_w[1][1] + sm_w[2][1] + sm_w[3][1]);
    }
}

// ---------------- fkpass: single fused pass over F (reads F ONCE, row-major coalesced) ----------------
// Replaces fpass (panel cast + colsum + sumsq) + klpass (KL terms): F was read twice (168 MB),
// and fpass's loads were dword-granular column-major. Key: in the panel layout [kc][kj][c][8e],
// the 8 e-values a column c needs are rows b0..b0+7 at column c — exactly what ONE lane loads
// across the r-loop (lane owns cols 4*lane..+3 of each chunk). So the transpose is LANE-PRIVATE:
// pack in registers (out0..out3, r statically unrolled per rule #20), no LDS staging, no
// strided loads. colsum: per-lane f32x4 partial -> LDS atomic (4-way) -> 1280 global atomics
// per block (655K total, spread over block completions; NOT the 16.8M burst of R4).
// Block = one kc (32 rows); wave w = kj group w (rows b0 = kc*32 + w*8 .. +7).
__device__ __forceinline__ void fkpass_body(const float* __restrict__ F,
                                            short* __restrict__ Fbt,
                                            float* __restrict__ colsum,
                                            float* __restrict__ acc, int kc) {
    __shared__ float csum[C_N];
    __shared__ float sm_red[4][2];
    int tid = threadIdx.x;
    int w = tid >> 6, lane = tid & 63;
    for (int i = tid; i < C_N; i += 256) csum[i] = 0.f;
    __syncthreads();

    int b0 = kc * 32 + w * 8;
    float s_acc[8], tt_acc[8];
#pragma unroll
    for (int r = 0; r < 8; r++) { s_acc[r] = 0.f; tt_acc[r] = 0.f; }
    float sq = 0.f;

    for (int cc = 0; cc < 5; cc++) {              // 5 chunks of 256 cols
        int cbase = cc * 256 + 4 * lane;
        f32x4 cs = { 0.f, 0.f, 0.f, 0.f };
        s16x8 out0, out1, out2, out3;             // 4 columns x 8 rows, lane-private transpose
#pragma unroll
        for (int r = 0; r < 8; r++) {
            float4 f = *(const float4*)(F + (size_t)(b0 + r) * C_N + cbase);
            float e0 = __expf(f.x), e1 = __expf(f.y), e2 = __expf(f.z), e3 = __expf(f.w);
            s_acc[r]  += e0 + e1 + e2 + e3;
            tt_acc[r] += e0 * f.x + e1 * f.y + e2 * f.z + e3 * f.w;
            cs.x += f.x; cs.y += f.y; cs.z += f.z; cs.w += f.w;
            sq += f.x * f.x + f.y * f.y + f.z * f.z + f.w * f.w;
            out0[r] = (short)f2bf(f.x);
            out1[r] = (short)f2bf(f.y);
            out2[r] = (short)f2bf(f.z);
            out3[r] = (short)f2bf(f.w);
        }
        short* dst = Fbt + ((size_t)(kc * 4 + w) * C_N + cbase) * 8;
        *(s16x8*)(dst)      = out0;               // columns cbase..cbase+3: 4 x 16B stores
        *(s16x8*)(dst + 8)  = out1;
        *(s16x8*)(dst + 16) = out2;
        *(s16x8*)(dst + 24) = out3;
        atomicAdd(&csum[cbase + 0], cs.x);        // LDS atomics, 4-way contention (one per wave)
        atomicAdd(&csum[cbase + 1], cs.y);
        atomicAdd(&csum[cbase + 2], cs.z);
        atomicAdd(&csum[cbase + 3], cs.w);
    }

    float kl_acc = 0.f;                           // kl_row = C*(tt/s); -sf recovered via colsum in final
#pragma unroll
    for (int r = 0; r < 8; r++) {
        float s = wave_red(s_acc[r]);
        float tt = wave_red(tt_acc[r]);
        if (lane == 0) kl_acc += (float)C_N * (tt / s);
    }
    sq = wave_red(sq);
    if (lane == 0) { sm_red[w][0] = sq; sm_red[w][1] = kl_acc; }
    __syncthreads();                              // csum complete + sm_red visible
    for (int i = tid; i < C_N; i += 256) atomicAdd(&colsum[i], csum[i]);
    if (tid == 0) {
        atomicAdd(&acc[A_SUMSQF], sm_red[0][0] + sm_red[1][0] + sm_red[2][0] + sm_red[3][0]);
        atomicAdd(&acc[A_KL],     sm_red[0][1] + sm_red[1][1] + sm_red[2][1] + sm_red[3][1]);
    }
}

// ---------------- bf16 Gram: S += X X^T, 2-phase pipelined, XCD-local K-chunks ----------------
// X: panel layout [kc][kj][Mp][8] bf16 (k = kc*32 + kj*8 + e).
// 128x128 tile, 4 waves (2x2 of 64x64), BK=32, 16x16x32 MFMA.
// LDS [128 rows][4 slots][8] with XOR swizzle: slot s at row r holds kj = s ^ (r&3).
// FOUR distinct static buffers, compile-time buffer identity (NoAlias for the legalizer).
// ONE barrier per K-step: stage(next) -> ds_read+MFMA(cur) -> __syncthreads. nt EVEN.
// Epilogue: PART -> plain stores into private partial slot [kc_blk][tile][128][128]
//           (R6 verified: removing the 16.8M-atomic burst took main 105 -> 70.6us);
//           !PART -> atomicAdd into the full matrix (ws too small for partials).
template<bool PART>
__device__ __forceinline__ void gram_body(const short* __restrict__ X,
                                          float* __restrict__ S,
                                          int Mp, int T, int ntri,
                                          int tile, int kc_blk, int k0step, int nt) {
    __shared__ __align__(16) short A0[128 * 32];
    __shared__ __align__(16) short A1[128 * 32];
    __shared__ __align__(16) short B0[128 * 32];
    __shared__ __align__(16) short B1[128 * 32];
    int tid = threadIdx.x;
    int bi = 0, rem = tile;
    while (rem >= T - bi) { rem -= T - bi; bi++; }
    int bj = bi + rem;
    int i0 = bi * 128, j0 = bj * 128;

    int wave = tid >> 6, lane = tid & 63;
    int wm = wave >> 1, wn = wave & 1;
    int quad = lane >> 4, l16 = lane & 15;

    const size_t kstep = (size_t)Mp * 32;       // shorts per 32-k step
    const short *pa0, *pa1, *pb0, *pb1;
    int lo0 = tid * 8, lo1 = (256 + tid) * 8;
    {
        int g0 = tid, g1 = 256 + tid;
        int r0 = g0 >> 2, r1 = g1 >> 2;
        int kj0 = (g0 & 3) ^ (r0 & 3), kj1 = (g1 & 3) ^ (r1 & 3);
        size_t base = (size_t)k0step * kstep;
        pa0 = X + base + ((size_t)kj0 * Mp + i0 + r0) * 8;
        pa1 = X + base + ((size_t)kj1 * Mp + i0 + r1) * 8;
        pb0 = X + base + ((size_t)kj0 * Mp + j0 + r0) * 8;
        pb1 = X + base + ((size_t)kj1 * Mp + j0 + r1) * 8;
    }

    f32x4 acc[4][4];
#pragma unroll
    for (int i = 0; i < 4; i++)
#pragma unroll
        for (int j = 0; j < 4; j++) acc[i][j] = { 0.f, 0.f, 0.f, 0.f };

    auto stage = [&](short* Ad, short* Bd) {
        __builtin_amdgcn_global_load_lds((const __attribute__((address_space(1))) unsigned int*)pa0,
                                         (__attribute__((address_space(3))) unsigned int*)(Ad + lo0), 16, 0, 0);
        __builtin_amdgcn_global_load_lds((const __attribute__((address_space(1))) unsigned int*)pa1,
                                         (__attribute__((address_space(3))) unsigned int*)(Ad + lo1), 16, 0, 0);
        __builtin_amdgcn_global_load_lds((const __attribute__((address_space(1))) unsigned int*)pb0,
                                         (__attribute__((address_space(3))) unsigned int*)(Bd + lo0), 16, 0, 0);
        __builtin_amdgcn_global_load_lds((const __attribute__((address_space(1))) unsigned int*)pb1,
                                         (__attribute__((address_space(3))) unsigned int*)(Bd + lo1), 16, 0, 0);
        pa0 += kstep; pa1 += kstep; pb0 += kstep; pb1 += kstep;
    };

    auto compute = [&](const short* Ab, const short* Bb) {
        s16x8 af[4], bfr[4];
#pragma unroll
        for (int f = 0; f < 4; f++) {
            int mrow = wm * 64 + f * 16 + l16;
            af[f] = *(const s16x8*)(Ab + mrow * 32 + (quad ^ (mrow & 3)) * 8);
            int nrow = wn * 64 + f * 16 + l16;
            bfr[f] = *(const s16x8*)(Bb + nrow * 32 + (quad ^ (nrow & 3)) * 8);
        }
        __builtin_amdgcn_s_setprio(1);
#pragma unroll
        for (int i = 0; i < 4; i++)
#pragma unroll
            for (int j = 0; j < 4; j++)
                acc[i][j] = __builtin_amdgcn_mfma_f32_16x16x32_bf16(af[i], bfr[j], acc[i][j], 0, 0, 0);
        __builtin_amdgcn_s_setprio(0);
    };

    stage(A0, B0);                               // prologue: k-step 0
    __syncthreads();                             // vmcnt(0) drain + barrier
    for (int t = 0; t < nt; t += 2) {
        stage(A1, B1);                           // k-step t+1 in flight under compute
        compute(A0, B0);
        __syncthreads();                         // drains vmcnt -> A1/B1 ready; A0/B0 reads done
        if (t + 2 < nt) stage(A0, B0);           // k-step t+2
        compute(A1, B1);
        __syncthreads();
    }

    if (PART) {
        float* Sp = S + (((size_t)kc_blk * ntri + tile) << 14);  // private [128][128] slot
#pragma unroll
        for (int i = 0; i < 4; i++)
#pragma unroll
            for (int j = 0; j < 4; j++)
#pragma unroll
                for (int r = 0; r < 4; r++) {
                    int lrow = wm * 64 + i * 16 + quad * 4 + r;
                    int lcol = wn * 64 + j * 16 + l16;
                    Sp[lrow * 128 + lcol] = acc[i][j][r];
                }
    } else {
#pragma unroll
        for (int i = 0; i < 4; i++)
#pragma unroll
            for (int j = 0; j < 4; j++)
#pragma unroll
                for (int r = 0; r < 4; r++) {
                    int grow = i0 + wm * 64 + i * 16 + quad * 4 + r;
                    int gcol = j0 + wn * 64 + j * 16 + l16;
                    atomicAdd(&S[(size_t)grow * Mp + gcol], acc[i][j][r]);
                }
    }
}

// ---------------- Frobenius^2 (+ optional mu^T S mu), per (tile, row-quarter) ----------------
// R6 lesson: 91 blocks with 3.6MB-strided partial reads = latency disaster at 0.35 blocks/CU.
// Now block = (tile, quarter q of 32 rows): each of the nks partial slices is a CONTIGUOUS
// 16KB stream (baseP + ks*pstride + q*4096 ...), 364 blocks. off-diag tiles weighted 2x.
__device__ __forceinline__ void fro_tile_any(const float* __restrict__ S,
                                             const float* __restrict__ mu_src,
                                             int Mp, int T, int ntri, int tile, int q,
                                             int nks, bool part,
                                             float* __restrict__ slotF,
                                             float* __restrict__ slotQ) {
    int bi = 0, rem = tile;
    while (rem >= T - bi) { rem -= T - bi; bi++; }
    int bj = bi + rem;
    const float invB = 1.f / (float)B_N;
    const float* baseP = S + ((size_t)tile << 14) + ((size_t)q << 12);   // partial path
    size_t pstride = (size_t)ntri << 14;
    size_t baseA = (size_t)(bi * 128 + q * 32) * Mp + (size_t)bj * 128;  // atomic path
    float sum = 0.f, qacc = 0.f;
    for (int e = threadIdx.x * 4; e < 4096; e += 1024) {                 // 32 rows x 128 cols
        int row = e >> 7, col = e & 127;
        float4 v;
        if (part) {
            v = *(const float4*)(baseP + e);
            for (int ks = 1; ks < nks; ks++) {
                float4 u = *(const float4*)(baseP + (size_t)ks * pstride + e);
                v.x += u.x; v.y += u.y; v.z += u.z; v.w += u.w;
            }
        } else {
            v = *(const float4*)(S + baseA + (size_t)row * Mp + col);
        }
        sum += v.x * v.x + v.y * v.y + v.z * v.z + v.w * v.w;
        if (mu_src) {
            float mr = mu_src[bi * 128 + q * 32 + row] * invB;
            float4 mc = *(const float4*)(mu_src + bj * 128 + col);
            qacc += mr * (v.x * mc.x + v.y * mc.y + v.z * mc.z + v.w * mc.w) * invB;
        }
    }
    sum = wave_red(sum);
    qacc = wave_red(qacc);
    __shared__ float sm_fro[4][2];
    int wid = threadIdx.x >> 6, lane = threadIdx.x & 63;
    if (lane == 0) { sm_fro[wid][0] = sum; sm_fro[wid][1] = qacc; }
    __syncthreads();
    if (threadIdx.x == 0) {
        float w = (bi == bj) ? 1.f : 2.f;
        atomicAdd(slotF, w * (sm_fro[0][0] + sm_fro[1][0] + sm_fro[2][0] + sm_fro[3][0]));
        if (mu_src)
            atomicAdd(slotQ, w * (sm_fro[0][1] + sm_fro[1][1] + sm_fro[2][1] + sm_fro[3][1]));
    }
}

// ================= fused kernels =================

// K1: blocks [0,512) fkpass | [512,672) wpass | [672,736) nll
//     | atomic path only: [736,836) zero G | [836,900) zero H.
__global__ __launch_bounds__(256) void prep_kernel(const float* __restrict__ lp,
                                                   const int* __restrict__ tgt,
                                                   const float* __restrict__ W,
                                                   const float* __restrict__ F,
                                                   short* __restrict__ Wb,
                                                   short* __restrict__ Fbt,
                                                   float* __restrict__ colsum,
                                                   float* __restrict__ acc,
                                                   float* __restrict__ G,
                                                   float* __restrict__ H) {
    int b = blockIdx.x;
    if (b < 512) {
        fkpass_body(F, Fbt, colsum, acc, b);
    } else if (b < 672) {
        wpass_body(W, Wb, acc, b - 512);
    } else if (b < 736) {
        nll_body(lp, tgt, acc, b - 672);
    } else if (b < 836) {
        float4* p = (float4*)G + (size_t)(b - 736) * 4096;   // 100 * 64KB = 6.5536 MB exact
        float4 z = { 0.f, 0.f, 0.f, 0.f };
        for (int i = threadIdx.x; i < 4096; i += 256) p[i] = z;
    } else {
        float4* p = (float4*)H + (size_t)(b - 836) * 4096;   // 64 * 64KB = 4.1943 MB exact
        float4 z = { 0.f, 0.f, 0.f, 0.f };
        for (int i = threadIdx.x; i < 4096; i += 256) p[i] = z;
    }
}

// K2: pure gram. blocks [0,880) gram G (55 tiles x 16 kc) | [880,1024) gram H (36 x 4).
// kc-minor decode keeps XCD(=blockIdx%8) on fixed K-regions (R3: FETCH 202->78MB).
// Atomic fallback staggers nt per kc so epilogue atomics spread across the window.
template<bool PART>
__global__ __launch_bounds__(256) void main_kernel(const short* __restrict__ Fbt,
                                                   float* __restrict__ G,
                                                   const short* __restrict__ Wb,
                                                   float* __restrict__ H) {
    const int G_NT[16] = {18,22,26,30,20,24,28,32,46,42,38,34,44,40,36,32};
    const int G_K0[16] = {0,18,40,66,96,116,140,168,200,246,288,326,360,404,444,480};
    const int H_NT[4]  = {8,10,12,10};
    const int H_K0[4]  = {0,8,18,30};
    int b = blockIdx.x;
    if (b < 880) {
        int tile = b >> 4, kc = b & 15;
        int k0 = PART ? kc * 32 : G_K0[kc];
        int nt = PART ? 32      : G_NT[kc];
        gram_body<PART>(Fbt, G, C_N, 10, 55, tile, kc, k0, nt);
    } else {
        int l = b - 880;                         // 880 % 8 == 0: local%8 == blockIdx%8
        int tile = l >> 2, kc = l & 3;
        int k0 = PART ? kc * 10 : H_K0[kc];
        int nt = PART ? 10      : H_NT[kc];
        gram_body<PART>(Wb, H, 1024, 8, 36, tile, kc, k0, nt);
    }
}

// K3: Frobenius reductions (+ mu^T G mu into A_FMU2) + last-block final combine.
// blocks: [0,220) G (tile,quarter) | [220,364) H (tile,quarter).
template<bool PART>
__global__ __launch_bounds__(256) void fro_final_kernel(const float* __restrict__ G,
                                                        const float* __restrict__ H,
                                                        float* __restrict__ acc,
                                                        const float* __restrict__ colsum,
                                                        unsigned* __restrict__ ticket,
                                                        float* __restrict__ out) {
    int b = blockIdx.x;
    if (b < 220) fro_tile_any(G, colsum, C_N, 10, 55, b >> 2, b & 3, 16, PART, acc + A_GFRO, acc + A_FMU2);
    else { int l = b - 220; fro_tile_any(H, nullptr, 1024, 8, 36, l >> 2, l & 3, 4, PART, acc + A_HFRO, nullptr); }

    __shared__ int amlast;
    if (threadIdx.x == 0) {
        __threadfence();                               // order my fro atomicAdds before ticket
        unsigned prev = atomicAdd(ticket, 1u);
        amlast = (prev == 363u);
    }
    __syncthreads();
    if (!amlast) return;
    __threadfence();                                   // acquire side

    // final combine (winner block only). colsum & prep-acc slots are prior-dispatch;
    // A_GFRO/A_HFRO/A_FMU2 are same-dispatch -> atomic read.
    float s = 0.f, s1 = 0.f;
    for (int c = threadIdx.x; c < C_N; c += 256) { float v = colsum[c]; s += v * v; s1 += v; }
    s = wave_red(s);
    s1 = wave_red(s1);
    __shared__ float sm[4][2];
    int wid = threadIdx.x >> 6, lane = threadIdx.x & 63;
    if (lane == 0) { sm[wid][0] = s; sm[wid][1] = s1; }
    __syncthreads();
    if (threadIdx.x == 0) {
        double musq_raw = (double)(sm[0][0] + sm[1][0] + sm[2][0] + sm[3][0]); // B^2*||mu||^2
        double sumF     = (double)(sm[0][1] + sm[1][1] + sm[2][1] + sm[3][1]); // Sum of all F
        double Bd = (double)B_N;
        double gfro = (double)atomicAdd(&acc[A_GFRO], 0.0f);
        double hfro = (double)atomicAdd(&acc[A_HFRO], 0.0f);
        double fmu2 = (double)atomicAdd(&acc[A_FMU2], 0.0f);         // mu^T G mu
        double nll = -((double)acc[A_NLL] / Bd);
        double kl  = ((double)acc[A_KL] - sumF) / Bd;                // fkpass omits -sf
        double trG = (double)acc[A_SUMSQF];
        double musq = musq_raw / (Bd * Bd);
        double cov = gfro / (Bd * Bd)
                   - (2.0 / Bd) * fmu2
                   + musq * musq
                   - 2.0 * (trG / Bd - musq)
                   + (double)C_N;
        double ortho = hfro - 2.0 * (double)acc[A_L2SQ] + (double)NCLS_N;
        double loss = 1.0 * nll + 0.2 * kl + 0.2 * cov + 0.1 * ortho
                    + 0.1 * (double)acc[A_L1] + 0.1 * sqrt((double)acc[A_L2SQ]);
        out[0] = (float)loss;
    }
}

extern "C" void kernel_launch(void* const* d_in, const int* in_sizes, int n_in,
                              void* d_out, int out_size, void* d_ws, size_t ws_size,
                              hipStream_t stream) {
    (void)in_sizes; (void)n_in; (void)out_size;
    const float* output_lp = (const float*)d_in[0];
    const int*   target    = (const int*)d_in[1];
    const float* W         = (const float*)d_in[2];
    const float* F         = (const float*)d_in[3];

    char*     ws     = (char*)d_ws;
    float*    acc    = (float*)(ws + ACC_OFF);
    unsigned* ticket = (unsigned*)(ws + TICKET_OFF);
    float*    colsum = (float*)(ws + COLSUM_OFF);
    short*    Fbt    = (short*)(ws + FBT_OFF);
    short*    Wb     = (short*)(ws + WB_OFF);

    bool part = (ws_size >= WS_PART_NEED);

    // acc + ticket + colsum must be zero BEFORE K1's atomics (ws poisoned before launch).
    hipMemsetAsync(ws, 0, 8192, stream);

    if (part) {
        // partial-store path: no G/H zero-init (every partial element is written).
        float* Gp = (float*)(ws + G_OFF);       // [16][55][128][128]
        float* Hp = (float*)(ws + HP_OFF);      // [4][36][128][128]
        prep_kernel<<<736, 256, 0, stream>>>(output_lp, target, W, F, Wb, Fbt, colsum, acc, Gp, Hp);
        main_kernel<true><<<1024, 256, 0, stream>>>(Fbt, Gp, Wb, Hp);
        fro_final_kernel<true><<<364, 256, 0, stream>>>(Gp, Hp, acc, colsum, ticket, (float*)d_out);
    } else {
        float* G = (float*)(ws + G_OFF);        // [1280][1280]
        float* H = (float*)(ws + H_OFF);        // [1024][1024]
        prep_kernel<<<900, 256, 0, stream>>>(output_lp, target, W, F, Wb, Fbt, colsum, acc, G, H);
        main_kernel<false><<<1024, 256, 0, stream>>>(Fbt, G, Wb, H);
        fro_final_kernel<false><<<364, 256, 0, stream>>>(G, H, acc, colsum, ticket, (float*)d_out);
    }
}